// Round 1
// baseline (664.413 us; speedup 1.0000x reference)
//
#include <hip/hip_runtime.h>

// ---------------------------------------------------------------------------
// TemporalHeteroConv on MI355X.  N=100000 nodes, E=800000 edges, C=64, H=4.
// Pipeline:
//   k_h      : h = x @ W_w + W_b                     (wave per node)
//   k_score  : es[e] = exp(leakyrelu(h_src.a1 + h_dst.a2 + b) * decay) per head
//              (16 lanes per edge, float4 chunks, shuffle-reduce over 16)
//   k_deg / scan1..3 / k_fill : CSR by destination (no sort)
//   k_main   : wave per node: softmax-normalized aggregation in registers,
//              proj (agg @ proj_w) from LDS, residual + LayerNorm + ReLU.
// Softmax max-subtraction dropped (shift-invariant; |scores| <~ 6 in fp32).
// ---------------------------------------------------------------------------

__device__ __forceinline__ float wred_sum(float v) {
  #pragma unroll
  for (int m = 32; m; m >>= 1) v += __shfl_xor(v, m, 64);
  return v;
}

// ---------------- h = x @ W + b (wave per node) ----------------
__global__ __launch_bounds__(256) void k_h(const float* __restrict__ x,
    const float* __restrict__ Ww, const float* __restrict__ Wb,
    float* __restrict__ h, int N)
{
  __shared__ float Wl[64 * 64];
  for (int i = threadIdx.x; i < 64 * 64; i += 256) Wl[i] = Ww[i];
  __syncthreads();
  const int c = threadIdx.x & 63;
  const int wid = blockIdx.x * 4 + (threadIdx.x >> 6);
  const int wstride = gridDim.x * 4;
  const float bj = Wb[c];
  for (int n = wid; n < N; n += wstride) {
    float xr = x[(size_t)n * 64 + c];
    float o = bj;
    #pragma unroll 8
    for (int k = 0; k < 64; ++k) {
      float xk = __shfl(xr, k, 64);
      o = fmaf(xk, Wl[k * 64 + c], o);
    }
    h[(size_t)n * 64 + c] = o;
  }
}

// ---------------- per-edge exp-scores, 16 lanes / edge ----------------
#define FMA4(P, S, R) { P.x = fmaf(S, R.x, P.x); P.y = fmaf(S, R.y, P.y); \
                        P.z = fmaf(S, R.z, P.z); P.w = fmaf(S, R.w, P.w); }

__global__ __launch_bounds__(256) void k_score(const float* __restrict__ h,
    const int* __restrict__ ei, const float* __restrict__ et,
    const int* __restrict__ ctime, const float* __restrict__ drate,
    const float* __restrict__ attn_w, const float* __restrict__ attn_b,
    float4* __restrict__ es, int E)
{
  const int lane = threadIdx.x & 63;
  const int sub  = lane >> 4;   // edge within wave (4 per wave)
  const int q    = lane & 15;   // 4-float chunk of the 64-channel row
  const int wid  = blockIdx.x * 4 + (threadIdx.x >> 6);
  int e = wid * 4 + sub;
  const bool valid = (e < E);
  if (!valid) e = E - 1;

  const int src = ei[e];
  const int dst = ei[E + e];
  const float4 hs = *(const float4*)(h + (size_t)src * 64 + q * 4);
  const float4 hd = *(const float4*)(h + (size_t)dst * 64 + q * 4);
  const float4* aw = (const float4*)attn_w;   // row r -> 4 head weights

  float4 p = make_float4(0.f, 0.f, 0.f, 0.f);
  float4 r;
  r = aw[q * 4 + 0];      FMA4(p, hs.x, r);
  r = aw[q * 4 + 1];      FMA4(p, hs.y, r);
  r = aw[q * 4 + 2];      FMA4(p, hs.z, r);
  r = aw[q * 4 + 3];      FMA4(p, hs.w, r);
  r = aw[64 + q * 4 + 0]; FMA4(p, hd.x, r);
  r = aw[64 + q * 4 + 1]; FMA4(p, hd.y, r);
  r = aw[64 + q * 4 + 2]; FMA4(p, hd.z, r);
  r = aw[64 + q * 4 + 3]; FMA4(p, hd.w, r);

  #pragma unroll
  for (int m = 1; m < 16; m <<= 1) {
    p.x += __shfl_xor(p.x, m, 64);
    p.y += __shfl_xor(p.y, m, 64);
    p.z += __shfl_xor(p.z, m, 64);
    p.w += __shfl_xor(p.w, m, 64);
  }

  const float4 ab = *(const float4*)attn_b;
  const float lam = log1pf(__expf(drate[0]));                 // softplus
  const float w = __expf(-lam * ((float)ctime[0] - et[e]));   // temporal decay

  float4 o; float t;
  t = p.x + ab.x; t = (t > 0.f ? t : 0.2f * t) * w; o.x = __expf(t);
  t = p.y + ab.y; t = (t > 0.f ? t : 0.2f * t) * w; o.y = __expf(t);
  t = p.z + ab.z; t = (t > 0.f ? t : 0.2f * t) * w; o.z = __expf(t);
  t = p.w + ab.w; t = (t > 0.f ? t : 0.2f * t) * w; o.w = __expf(t);

  if (valid && q == 0) es[e] = o;
}

// ---------------- CSR build ----------------
__global__ __launch_bounds__(256) void k_deg(const int* __restrict__ ei,
    int* __restrict__ deg, int E)
{
  int e = blockIdx.x * 256 + threadIdx.x;
  if (e < E) atomicAdd(&deg[ei[E + e]], 1);
}

__global__ __launch_bounds__(256) void scan1(const int* __restrict__ deg,
    int* __restrict__ offs, int* __restrict__ bsums, int N)
{
  int i = blockIdx.x * 256 + threadIdx.x;
  int lane = threadIdx.x & 63;
  int w = threadIdx.x >> 6;
  int v = (i < N) ? deg[i] : 0;
  int s = v;
  #pragma unroll
  for (int d = 1; d < 64; d <<= 1) {
    int t = __shfl_up(s, d, 64);
    if (lane >= d) s += t;
  }
  __shared__ int wsum[4];
  if (lane == 63) wsum[w] = s;
  __syncthreads();
  int add = 0;
  if (w > 0) add += wsum[0];
  if (w > 1) add += wsum[1];
  if (w > 2) add += wsum[2];
  if (i < N) offs[i] = s - v + add;                 // block-exclusive
  if (threadIdx.x == 255) bsums[blockIdx.x] = wsum[0] + wsum[1] + wsum[2] + wsum[3];
}

__global__ __launch_bounds__(512) void scan2(int* bsums, int NB)
{
  __shared__ int lds[512];
  int t = threadIdx.x;
  int v = (t < NB) ? bsums[t] : 0;
  lds[t] = v;
  __syncthreads();
  for (int s = 1; s < 512; s <<= 1) {
    int a = (t >= s) ? lds[t - s] : 0;
    __syncthreads();
    lds[t] += a;
    __syncthreads();
  }
  if (t < NB) bsums[t] = lds[t] - v;                // exclusive
}

__global__ __launch_bounds__(256) void scan3(int* __restrict__ offs,
    const int* __restrict__ bsums, int N, int E)
{
  int i = blockIdx.x * 256 + threadIdx.x;
  if (i < N) offs[i] += bsums[blockIdx.x];
  if (i == N) offs[N] = E;
}

__global__ __launch_bounds__(256) void k_fill(const int* __restrict__ ei,
    const int* __restrict__ offs, int* __restrict__ cursor,
    int2* __restrict__ csr, int E)
{
  int e = blockIdx.x * 256 + threadIdx.x;
  if (e >= E) return;
  int s = ei[e], d = ei[E + e];
  int pos = offs[d] + atomicAdd(&cursor[d], 1);
  csr[pos] = make_int2(s, e);
}

// ---------------- aggregation + proj + LN (wave per node) ----------------
__global__ __launch_bounds__(256) void k_main(const float* __restrict__ h,
    const float* __restrict__ x,
    const int2* __restrict__ csr, const int* __restrict__ offs,
    const float4* __restrict__ es,
    const float* __restrict__ Pw, const float* __restrict__ Pb,
    const float* __restrict__ lg, const float* __restrict__ lb,
    float* __restrict__ out, int N)
{
  __shared__ float Pl[256 * 64];    // 64 KB: proj_w, row-major [k][j]
  __shared__ float aggst[4 * 256];  // per-wave agg row staging
  for (int i = threadIdx.x; i < 256 * 64; i += 256) Pl[i] = Pw[i];
  __syncthreads();

  const int c = threadIdx.x & 63;
  const int wv = threadIdx.x >> 6;
  const int wid = blockIdx.x * 4 + wv;
  const int wstride = gridDim.x * 4;
  const float pbj = Pb[c], gj = lg[c], bj = lb[c];
  float* ag = &aggst[wv * 256];

  for (int n0 = wid; n0 < N; n0 += wstride) {
    const int n = __builtin_amdgcn_readfirstlane(n0);
    const int p0 = offs[n], p1 = offs[n + 1];

    float acc0 = 0.f, acc1 = 0.f, acc2 = 0.f, acc3 = 0.f;
    float den0 = 0.f, den1 = 0.f, den2 = 0.f, den3 = 0.f;
    for (int p = p0; p < p1; ++p) {
      int2 se = csr[p];                       // wave-uniform -> s_load
      float4 ev = es[se.y];                   // wave-uniform -> s_load
      float hs = h[(size_t)se.x * 64 + c];    // coalesced 256B gather
      den0 += ev.x; den1 += ev.y; den2 += ev.z; den3 += ev.w;
      acc0 = fmaf(ev.x, hs, acc0);
      acc1 = fmaf(ev.y, hs, acc1);
      acc2 = fmaf(ev.z, hs, acc2);
      acc3 = fmaf(ev.w, hs, acc3);
    }
    float4 g;
    g.x = acc0 / (den0 + 1e-8f);
    g.y = acc1 / (den1 + 1e-8f);
    g.z = acc2 / (den2 + 1e-8f);
    g.w = acc3 / (den3 + 1e-8f);

    // stage agg row (k = c*4 + head) into LDS for the proj dot products.
    __builtin_amdgcn_wave_barrier();
    *(float4*)&ag[c * 4] = g;
    __builtin_amdgcn_wave_barrier();

    float o = pbj;
    #pragma unroll 8
    for (int kk = 0; kk < 64; ++kk) {
      float4 a4 = *(const float4*)&ag[kk * 4];   // broadcast read
      const float* Pr = &Pl[kk * 256 + c];
      o = fmaf(a4.x, Pr[0],   o);
      o = fmaf(a4.y, Pr[64],  o);
      o = fmaf(a4.z, Pr[128], o);
      o = fmaf(a4.w, Pr[192], o);
    }
    __builtin_amdgcn_wave_barrier();

    float z = o + x[(size_t)n * 64 + c];
    float mu = wred_sum(z) * 0.015625f;
    float dz = z - mu;
    float var = wred_sum(dz * dz) * 0.015625f;
    float y = fmaf(gj * dz, rsqrtf(var + 1e-5f), bj);
    out[(size_t)n * 64 + c] = fmaxf(y, 0.f);
  }
}

// ---------------------------------------------------------------------------
extern "C" void kernel_launch(void* const* d_in, const int* in_sizes, int n_in,
                              void* d_out, int out_size, void* d_ws, size_t ws_size,
                              hipStream_t stream)
{
  const float* x  = (const float*)d_in[0];
  const int*   ei = (const int*)d_in[1];
  const float* et = (const float*)d_in[2];
  const int*   ct = (const int*)d_in[3];
  const float* Ww = (const float*)d_in[4];
  const float* Wb = (const float*)d_in[5];
  const float* aw = (const float*)d_in[6];
  const float* ab = (const float*)d_in[7];
  const float* dr = (const float*)d_in[8];
  const float* Pw = (const float*)d_in[9];
  const float* Pb = (const float*)d_in[10];
  const float* lg = (const float*)d_in[11];
  const float* lb = (const float*)d_in[12];
  float* out = (float*)d_out;

  const int N = in_sizes[0] / 64;
  const int E = in_sizes[2];

  char* ws = (char*)d_ws;
  size_t off = 0;
  auto take = [&](size_t bytes) -> char* {
    char* p = ws + off;
    off = (off + bytes + 255) & ~(size_t)255;
    return p;
  };
  float*  h      = (float*)take((size_t)N * 64 * 4);
  int*    deg    = (int*)take((size_t)N * 4 * 2);   // deg + cursor contiguous
  int*    cursor = deg + N;
  int*    offs   = (int*)take((size_t)(N + 1) * 4);
  int*    bsums  = (int*)take(512 * 4);
  int2*   csr    = (int2*)take((size_t)E * 8);
  float4* es     = (float4*)take((size_t)E * 16);

  hipMemsetAsync(deg, 0, (size_t)N * 8, stream);    // zero deg + cursor

  k_h<<<1024, 256, 0, stream>>>(x, Ww, Wb, h, N);
  k_score<<<(E + 15) / 16, 256, 0, stream>>>(h, ei, et, ct, dr, aw, ab, es, E);
  k_deg<<<(E + 255) / 256, 256, 0, stream>>>(ei, deg, E);
  const int NB = (N + 255) / 256;
  scan1<<<NB, 256, 0, stream>>>(deg, offs, bsums, N);
  scan2<<<1, 512, 0, stream>>>(bsums, NB);
  scan3<<<NB, 256, 0, stream>>>(offs, bsums, N, E);
  k_fill<<<(E + 255) / 256, 256, 0, stream>>>(ei, offs, cursor, csr, E);
  k_main<<<512, 256, 0, stream>>>(h, x, csr, offs, es, Pw, Pb, lg, lb, out, N);
}

// Round 2
// 532.768 us; speedup vs baseline: 1.2471x; 1.2471x over previous
//
#include <hip/hip_runtime.h>

// ---------------------------------------------------------------------------
// TemporalHeteroConv on MI355X.  N=100000 nodes, E=800000 edges, C=64, H=4.
// Pipeline:
//   k_h      : h = x @ W_w + W_b                      (wave per node)
//   k_score  : es[e] = exp(leakyrelu(...)*decay) per head (16 lanes/edge)
//   k_deg / scan1..3 / k_fill : CSR by destination
//   k_agg    : wave per node, softmax-normalized aggregation in registers,
//              NO LDS, prefetched edge loop, writes agg rows in bf16.
//   k_proj   : lane = node. out = agg @ proj_w via SMEM-broadcast P (s_load)
//              + pure VALU FMA; fused residual + LayerNorm + ReLU, in-register
//              LN (no shuffles, no LDS).  [k_main r1 was LDS-issue-bound:
//              320 LDS ops/node ~= 2000 cy/node ~= the whole 305us]
// ---------------------------------------------------------------------------

__device__ __forceinline__ unsigned short f2bf(float f) {
  unsigned int u = __float_as_uint(f);
  u += 0x7FFFu + ((u >> 16) & 1u);          // RNE
  return (unsigned short)(u >> 16);
}

// ---------------- h = x @ W + b (wave per node) ----------------
__global__ __launch_bounds__(256) void k_h(const float* __restrict__ x,
    const float* __restrict__ Ww, const float* __restrict__ Wb,
    float* __restrict__ h, int N)
{
  __shared__ float Wl[64 * 64];
  for (int i = threadIdx.x; i < 64 * 64; i += 256) Wl[i] = Ww[i];
  __syncthreads();
  const int c = threadIdx.x & 63;
  const int wid = blockIdx.x * 4 + (threadIdx.x >> 6);
  const int wstride = gridDim.x * 4;
  const float bj = Wb[c];
  for (int n = wid; n < N; n += wstride) {
    float xr = x[(size_t)n * 64 + c];
    float o = bj;
    #pragma unroll 8
    for (int k = 0; k < 64; ++k) {
      float xk = __shfl(xr, k, 64);
      o = fmaf(xk, Wl[k * 64 + c], o);
    }
    h[(size_t)n * 64 + c] = o;
  }
}

// ---------------- per-edge exp-scores, 16 lanes / edge ----------------
#define FMA4(P, S, R) { P.x = fmaf(S, R.x, P.x); P.y = fmaf(S, R.y, P.y); \
                        P.z = fmaf(S, R.z, P.z); P.w = fmaf(S, R.w, P.w); }

__global__ __launch_bounds__(256) void k_score(const float* __restrict__ h,
    const int* __restrict__ ei, const float* __restrict__ et,
    const int* __restrict__ ctime, const float* __restrict__ drate,
    const float* __restrict__ attn_w, const float* __restrict__ attn_b,
    float4* __restrict__ es, int E)
{
  const int lane = threadIdx.x & 63;
  const int sub  = lane >> 4;
  const int q    = lane & 15;
  const int wid  = blockIdx.x * 4 + (threadIdx.x >> 6);
  int e = wid * 4 + sub;
  const bool valid = (e < E);
  if (!valid) e = E - 1;

  const int src = ei[e];
  const int dst = ei[E + e];
  const float4 hs = *(const float4*)(h + (size_t)src * 64 + q * 4);
  const float4 hd = *(const float4*)(h + (size_t)dst * 64 + q * 4);
  const float4* aw = (const float4*)attn_w;

  float4 p = make_float4(0.f, 0.f, 0.f, 0.f);
  float4 r;
  r = aw[q * 4 + 0];      FMA4(p, hs.x, r);
  r = aw[q * 4 + 1];      FMA4(p, hs.y, r);
  r = aw[q * 4 + 2];      FMA4(p, hs.z, r);
  r = aw[q * 4 + 3];      FMA4(p, hs.w, r);
  r = aw[64 + q * 4 + 0]; FMA4(p, hd.x, r);
  r = aw[64 + q * 4 + 1]; FMA4(p, hd.y, r);
  r = aw[64 + q * 4 + 2]; FMA4(p, hd.z, r);
  r = aw[64 + q * 4 + 3]; FMA4(p, hd.w, r);

  #pragma unroll
  for (int m = 1; m < 16; m <<= 1) {
    p.x += __shfl_xor(p.x, m, 64);
    p.y += __shfl_xor(p.y, m, 64);
    p.z += __shfl_xor(p.z, m, 64);
    p.w += __shfl_xor(p.w, m, 64);
  }

  const float4 ab = *(const float4*)attn_b;
  const float lam = log1pf(__expf(drate[0]));
  const float w = __expf(-lam * ((float)ctime[0] - et[e]));

  float4 o; float t;
  t = p.x + ab.x; t = (t > 0.f ? t : 0.2f * t) * w; o.x = __expf(t);
  t = p.y + ab.y; t = (t > 0.f ? t : 0.2f * t) * w; o.y = __expf(t);
  t = p.z + ab.z; t = (t > 0.f ? t : 0.2f * t) * w; o.z = __expf(t);
  t = p.w + ab.w; t = (t > 0.f ? t : 0.2f * t) * w; o.w = __expf(t);

  if (valid && q == 0) es[e] = o;
}

// ---------------- CSR build ----------------
__global__ __launch_bounds__(256) void k_deg(const int* __restrict__ ei,
    int* __restrict__ deg, int E)
{
  int e = blockIdx.x * 256 + threadIdx.x;
  if (e < E) atomicAdd(&deg[ei[E + e]], 1);
}

__global__ __launch_bounds__(256) void scan1(const int* __restrict__ deg,
    int* __restrict__ offs, int* __restrict__ bsums, int N)
{
  int i = blockIdx.x * 256 + threadIdx.x;
  int lane = threadIdx.x & 63;
  int w = threadIdx.x >> 6;
  int v = (i < N) ? deg[i] : 0;
  int s = v;
  #pragma unroll
  for (int d = 1; d < 64; d <<= 1) {
    int t = __shfl_up(s, d, 64);
    if (lane >= d) s += t;
  }
  __shared__ int wsum[4];
  if (lane == 63) wsum[w] = s;
  __syncthreads();
  int add = 0;
  if (w > 0) add += wsum[0];
  if (w > 1) add += wsum[1];
  if (w > 2) add += wsum[2];
  if (i < N) offs[i] = s - v + add;
  if (threadIdx.x == 255) bsums[blockIdx.x] = wsum[0] + wsum[1] + wsum[2] + wsum[3];
}

__global__ __launch_bounds__(512) void scan2(int* bsums, int NB)
{
  __shared__ int lds[512];
  int t = threadIdx.x;
  int v = (t < NB) ? bsums[t] : 0;
  lds[t] = v;
  __syncthreads();
  for (int s = 1; s < 512; s <<= 1) {
    int a = (t >= s) ? lds[t - s] : 0;
    __syncthreads();
    lds[t] += a;
    __syncthreads();
  }
  if (t < NB) bsums[t] = lds[t] - v;
}

__global__ __launch_bounds__(256) void scan3(int* __restrict__ offs,
    const int* __restrict__ bsums, int N, int E)
{
  int i = blockIdx.x * 256 + threadIdx.x;
  if (i < N) offs[i] += bsums[blockIdx.x];
  if (i == N) offs[N] = E;
}

__global__ __launch_bounds__(256) void k_fill(const int* __restrict__ ei,
    const int* __restrict__ offs, int* __restrict__ cursor,
    int2* __restrict__ csr, int E)
{
  int e = blockIdx.x * 256 + threadIdx.x;
  if (e >= E) return;
  int s = ei[e], d = ei[E + e];
  int pos = offs[d] + atomicAdd(&cursor[d], 1);
  csr[pos] = make_int2(s, e);
}

// ---------------- aggregation (wave per node, no LDS) ----------------
__global__ __launch_bounds__(256) void k_agg(const float* __restrict__ h,
    const int2* __restrict__ csr, const int* __restrict__ offs,
    const float4* __restrict__ es, unsigned short* __restrict__ agg, int N)
{
  const int c = threadIdx.x & 63;
  const int wid = blockIdx.x * 4 + (threadIdx.x >> 6);
  const int wstride = gridDim.x * 4;

  for (int n0 = wid; n0 < N; n0 += wstride) {
    const int n = __builtin_amdgcn_readfirstlane(n0);
    const int p0 = offs[n], p1 = offs[n + 1];

    float acc0 = 0.f, acc1 = 0.f, acc2 = 0.f, acc3 = 0.f;
    float den0 = 0.f, den1 = 0.f, den2 = 0.f, den3 = 0.f;

    int2 se = make_int2(0, 0);
    float4 ev = make_float4(0.f, 0.f, 0.f, 0.f);
    if (p0 < p1) { se = csr[p0]; ev = es[se.y]; }

    for (int p = p0; p < p1; ++p) {
      float hs = h[(size_t)se.x * 64 + c];      // coalesced 256B gather
      int2 se2 = se; float4 ev2 = ev;
      if (p + 1 < p1) { se2 = csr[p + 1]; ev2 = es[se2.y]; }  // prefetch
      den0 += ev.x; den1 += ev.y; den2 += ev.z; den3 += ev.w;
      acc0 = fmaf(ev.x, hs, acc0);
      acc1 = fmaf(ev.y, hs, acc1);
      acc2 = fmaf(ev.z, hs, acc2);
      acc3 = fmaf(ev.w, hs, acc3);
      se = se2; ev = ev2;
    }
    ushort4 o;
    o.x = f2bf(acc0 / (den0 + 1e-8f));
    o.y = f2bf(acc1 / (den1 + 1e-8f));
    o.z = f2bf(acc2 / (den2 + 1e-8f));
    o.w = f2bf(acc3 / (den3 + 1e-8f));
    *(ushort4*)(agg + (size_t)n * 256 + c * 4) = o;   // coalesced b64
  }
}

// ---------------- proj + residual + LN + ReLU (lane = node) ----------------
__global__ __launch_bounds__(256) void k_proj(const unsigned short* __restrict__ agg,
    const float* __restrict__ x,
    const float* __restrict__ Pw, const float* __restrict__ Pb,
    const float* __restrict__ lg, const float* __restrict__ lb,
    float* __restrict__ out, int N)
{
  const int lane = threadIdx.x & 63;
  const int wv = threadIdx.x >> 6;
  const int n = (blockIdx.x * 4 + wv) * 64 + lane;
  const bool valid = (n < N);
  const int nc = valid ? n : (N - 1);

  float o[64];
  #pragma unroll
  for (int c = 0; c < 64; ++c) o[c] = Pb[c];          // uniform -> s_load

  const unsigned short* arow = agg + (size_t)nc * 256;

  for (int ch = 0; ch < 16; ++ch) {                   // 16 chunks x 16 k
    uint4 u0 = *(const uint4*)(arow + ch * 16);       // 8 bf16
    uint4 u1 = *(const uint4*)(arow + ch * 16 + 8);   // 8 bf16
    float a[16];
    unsigned int uu[8] = {u0.x, u0.y, u0.z, u0.w, u1.x, u1.y, u1.z, u1.w};
    #pragma unroll
    for (int i = 0; i < 8; ++i) {
      a[2 * i]     = __uint_as_float(uu[i] << 16);
      a[2 * i + 1] = __uint_as_float(uu[i] & 0xFFFF0000u);
    }
    #pragma unroll
    for (int kk = 0; kk < 16; ++kk) {
      const float* Pr = Pw + (size_t)(ch * 16 + kk) * 64;  // uniform row
      #pragma unroll
      for (int c = 0; c < 64; ++c)
        o[c] = fmaf(a[kk], Pr[c], o[c]);              // v_fmac v, s, v
    }
  }

  // residual
  const float* xr = x + (size_t)nc * 64;
  #pragma unroll
  for (int c4 = 0; c4 < 16; ++c4) {
    float4 xv = *(const float4*)(xr + c4 * 4);
    o[c4 * 4 + 0] += xv.x; o[c4 * 4 + 1] += xv.y;
    o[c4 * 4 + 2] += xv.z; o[c4 * 4 + 3] += xv.w;
  }

  // in-register LayerNorm (pairwise trees)
  float r[32];
  #pragma unroll
  for (int i = 0; i < 32; ++i) r[i] = o[i] + o[i + 32];
  #pragma unroll
  for (int st = 16; st >= 1; st >>= 1) {
    #pragma unroll
    for (int i = 0; i < 16; ++i)
      if (i < st) r[i] += r[i + st];
  }
  const float mu = r[0] * 0.015625f;

  #pragma unroll
  for (int i = 0; i < 32; ++i) {
    float d0 = o[i] - mu, d1 = o[i + 32] - mu;
    r[i] = fmaf(d0, d0, d1 * d1);
  }
  #pragma unroll
  for (int st = 16; st >= 1; st >>= 1) {
    #pragma unroll
    for (int i = 0; i < 16; ++i)
      if (i < st) r[i] += r[i + st];
  }
  const float inv = rsqrtf(r[0] * 0.015625f + 1e-5f);

  if (valid) {
    float* outr = out + (size_t)n * 64;
    #pragma unroll
    for (int c4 = 0; c4 < 16; ++c4) {
      float4 y;
      y.x = fmaxf(fmaf(lg[c4*4+0] * (o[c4*4+0] - mu), inv, lb[c4*4+0]), 0.f);
      y.y = fmaxf(fmaf(lg[c4*4+1] * (o[c4*4+1] - mu), inv, lb[c4*4+1]), 0.f);
      y.z = fmaxf(fmaf(lg[c4*4+2] * (o[c4*4+2] - mu), inv, lb[c4*4+2]), 0.f);
      y.w = fmaxf(fmaf(lg[c4*4+3] * (o[c4*4+3] - mu), inv, lb[c4*4+3]), 0.f);
      *(float4*)(outr + c4 * 4) = y;
    }
  }
}

// ---------------------------------------------------------------------------
extern "C" void kernel_launch(void* const* d_in, const int* in_sizes, int n_in,
                              void* d_out, int out_size, void* d_ws, size_t ws_size,
                              hipStream_t stream)
{
  const float* x  = (const float*)d_in[0];
  const int*   ei = (const int*)d_in[1];
  const float* et = (const float*)d_in[2];
  const int*   ct = (const int*)d_in[3];
  const float* Ww = (const float*)d_in[4];
  const float* Wb = (const float*)d_in[5];
  const float* aw = (const float*)d_in[6];
  const float* ab = (const float*)d_in[7];
  const float* dr = (const float*)d_in[8];
  const float* Pw = (const float*)d_in[9];
  const float* Pb = (const float*)d_in[10];
  const float* lg = (const float*)d_in[11];
  const float* lb = (const float*)d_in[12];
  float* out = (float*)d_out;

  const int N = in_sizes[0] / 64;
  const int E = in_sizes[2];

  char* ws = (char*)d_ws;
  size_t off = 0;
  auto take = [&](size_t bytes) -> char* {
    char* p = ws + off;
    off = (off + bytes + 255) & ~(size_t)255;
    return p;
  };
  float*  h      = (float*)take((size_t)N * 64 * 4);
  int*    deg    = (int*)take((size_t)N * 4 * 2);
  int*    cursor = deg + N;
  int*    offs   = (int*)take((size_t)(N + 1) * 4);
  int*    bsums  = (int*)take(512 * 4);
  int2*   csr    = (int2*)take((size_t)E * 8);
  float4* es     = (float4*)take((size_t)E * 16);
  unsigned short* agg = (unsigned short*)take((size_t)N * 256 * 2);

  hipMemsetAsync(deg, 0, (size_t)N * 8, stream);

  k_h<<<1024, 256, 0, stream>>>(x, Ww, Wb, h, N);
  k_score<<<(E + 15) / 16, 256, 0, stream>>>(h, ei, et, ct, dr, aw, ab, es, E);
  k_deg<<<(E + 255) / 256, 256, 0, stream>>>(ei, deg, E);
  const int NB = (N + 255) / 256;
  scan1<<<NB, 256, 0, stream>>>(deg, offs, bsums, N);
  scan2<<<1, 512, 0, stream>>>(bsums, NB);
  scan3<<<NB, 256, 0, stream>>>(offs, bsums, N, E);
  k_fill<<<(E + 255) / 256, 256, 0, stream>>>(ei, offs, cursor, csr, E);
  k_agg<<<2048, 256, 0, stream>>>(h, csr, offs, es, agg, N);
  k_proj<<<(N + 255) / 256, 256, 0, stream>>>(agg, x, Pw, Pb, lg, lb, out, N);
}

// Round 3
// 463.101 us; speedup vs baseline: 1.4347x; 1.1504x over previous
//
#include <hip/hip_runtime.h>

// ---------------------------------------------------------------------------
// TemporalHeteroConv on MI355X.  N=100000 nodes, E=800000 edges, C=64, H=4.
// Pipeline:
//   k_h      : h = x @ W_w + W_b  (wave/node); also writes h16 (bf16 copy)
//   k_uv     : u = h@a1, v = h@a2  (N x 4 each) -- GAT factorization so the
//              per-edge score needs only u[src]+v[dst], not two 256B h rows.
//              [r2: k_score gathered 512B/edge -> 180MB HBM, 115us]
//   k_score  : thread/edge: es[e] = exp(leakyrelu(u+v+b)*decay)  (32B gather)
//   k_deg / scan1..3 / k_fill : CSR by destination
//   k_agg    : wave/node, bf16 h gather (128B/edge), csr->es->h prefetch
//              pipelined one full iteration ahead; agg rows in bf16.
//   k_proj   : lane = node; agg @ proj_w via scalar-broadcast P, in-register
//              residual + LayerNorm + ReLU.
// ---------------------------------------------------------------------------

__device__ __forceinline__ unsigned short f2bf(float f) {
  unsigned int u = __float_as_uint(f);
  u += 0x7FFFu + ((u >> 16) & 1u);          // RNE
  return (unsigned short)(u >> 16);
}
__device__ __forceinline__ float bf2f(unsigned short s) {
  return __uint_as_float(((unsigned int)s) << 16);
}

#define FMA4(P, S, R) { P.x = fmaf(S, R.x, P.x); P.y = fmaf(S, R.y, P.y); \
                        P.z = fmaf(S, R.z, P.z); P.w = fmaf(S, R.w, P.w); }

// ---------------- h = x @ W + b (wave per node), fp32 + bf16 copies --------
__global__ __launch_bounds__(256) void k_h(const float* __restrict__ x,
    const float* __restrict__ Ww, const float* __restrict__ Wb,
    float* __restrict__ h, unsigned short* __restrict__ h16, int N)
{
  __shared__ float Wl[64 * 64];
  for (int i = threadIdx.x; i < 64 * 64; i += 256) Wl[i] = Ww[i];
  __syncthreads();
  const int c = threadIdx.x & 63;
  const int wid = blockIdx.x * 4 + (threadIdx.x >> 6);
  const int wstride = gridDim.x * 4;
  const float bj = Wb[c];
  for (int n = wid; n < N; n += wstride) {
    float xr = x[(size_t)n * 64 + c];
    float o = bj;
    #pragma unroll 8
    for (int k = 0; k < 64; ++k) {
      float xk = __shfl(xr, k, 64);
      o = fmaf(xk, Wl[k * 64 + c], o);
    }
    h[(size_t)n * 64 + c] = o;
    h16[(size_t)n * 64 + c] = f2bf(o);
  }
}

// ---------------- u = h @ a1, v = h @ a2 (16 lanes / node) -----------------
__global__ __launch_bounds__(256) void k_uv(const float* __restrict__ h,
    const float* __restrict__ attn_w, float4* __restrict__ u,
    float4* __restrict__ v, int N)
{
  const int lane = threadIdx.x & 63;
  const int sub  = lane >> 4;
  const int q    = lane & 15;
  const int wid  = blockIdx.x * 4 + (threadIdx.x >> 6);
  int n = wid * 4 + sub;
  const bool valid = (n < N);
  const int nc = valid ? n : (N - 1);

  const float4 hs = *(const float4*)(h + (size_t)nc * 64 + q * 4);
  const float4* aw = (const float4*)attn_w;   // row r -> 4 head weights

  float4 p1 = make_float4(0.f, 0.f, 0.f, 0.f);
  float4 p2 = make_float4(0.f, 0.f, 0.f, 0.f);
  float4 r;
  r = aw[q * 4 + 0];      FMA4(p1, hs.x, r);
  r = aw[q * 4 + 1];      FMA4(p1, hs.y, r);
  r = aw[q * 4 + 2];      FMA4(p1, hs.z, r);
  r = aw[q * 4 + 3];      FMA4(p1, hs.w, r);
  r = aw[64 + q * 4 + 0]; FMA4(p2, hs.x, r);
  r = aw[64 + q * 4 + 1]; FMA4(p2, hs.y, r);
  r = aw[64 + q * 4 + 2]; FMA4(p2, hs.z, r);
  r = aw[64 + q * 4 + 3]; FMA4(p2, hs.w, r);

  #pragma unroll
  for (int m = 1; m < 16; m <<= 1) {
    p1.x += __shfl_xor(p1.x, m, 64); p1.y += __shfl_xor(p1.y, m, 64);
    p1.z += __shfl_xor(p1.z, m, 64); p1.w += __shfl_xor(p1.w, m, 64);
    p2.x += __shfl_xor(p2.x, m, 64); p2.y += __shfl_xor(p2.y, m, 64);
    p2.z += __shfl_xor(p2.z, m, 64); p2.w += __shfl_xor(p2.w, m, 64);
  }
  if (valid && q == 0) { u[n] = p1; v[n] = p2; }
}

// ---------------- per-edge exp-scores (thread per edge) --------------------
__global__ __launch_bounds__(256) void k_score(const float4* __restrict__ u,
    const float4* __restrict__ v,
    const int* __restrict__ ei, const float* __restrict__ et,
    const int* __restrict__ ctime, const float* __restrict__ drate,
    const float* __restrict__ attn_b, float4* __restrict__ es, int E)
{
  int e = blockIdx.x * 256 + threadIdx.x;
  if (e >= E) return;
  const int src = ei[e];
  const int dst = ei[E + e];
  const float4 us = u[src];
  const float4 vd = v[dst];
  const float4 ab = *(const float4*)attn_b;
  const float lam = log1pf(__expf(drate[0]));                 // softplus
  const float w = __expf(-lam * ((float)ctime[0] - et[e]));   // decay

  float4 o; float t;
  t = us.x + vd.x + ab.x; t = (t > 0.f ? t : 0.2f * t) * w; o.x = __expf(t);
  t = us.y + vd.y + ab.y; t = (t > 0.f ? t : 0.2f * t) * w; o.y = __expf(t);
  t = us.z + vd.z + ab.z; t = (t > 0.f ? t : 0.2f * t) * w; o.z = __expf(t);
  t = us.w + vd.w + ab.w; t = (t > 0.f ? t : 0.2f * t) * w; o.w = __expf(t);
  es[e] = o;
}

// ---------------- CSR build ----------------
__global__ __launch_bounds__(256) void k_deg(const int* __restrict__ ei,
    int* __restrict__ deg, int E)
{
  int e = blockIdx.x * 256 + threadIdx.x;
  if (e < E) atomicAdd(&deg[ei[E + e]], 1);
}

__global__ __launch_bounds__(256) void scan1(const int* __restrict__ deg,
    int* __restrict__ offs, int* __restrict__ bsums, int N)
{
  int i = blockIdx.x * 256 + threadIdx.x;
  int lane = threadIdx.x & 63;
  int w = threadIdx.x >> 6;
  int v = (i < N) ? deg[i] : 0;
  int s = v;
  #pragma unroll
  for (int d = 1; d < 64; d <<= 1) {
    int t = __shfl_up(s, d, 64);
    if (lane >= d) s += t;
  }
  __shared__ int wsum[4];
  if (lane == 63) wsum[w] = s;
  __syncthreads();
  int add = 0;
  if (w > 0) add += wsum[0];
  if (w > 1) add += wsum[1];
  if (w > 2) add += wsum[2];
  if (i < N) offs[i] = s - v + add;
  if (threadIdx.x == 255) bsums[blockIdx.x] = wsum[0] + wsum[1] + wsum[2] + wsum[3];
}

__global__ __launch_bounds__(512) void scan2(int* bsums, int NB)
{
  __shared__ int lds[512];
  int t = threadIdx.x;
  int v = (t < NB) ? bsums[t] : 0;
  lds[t] = v;
  __syncthreads();
  for (int s = 1; s < 512; s <<= 1) {
    int a = (t >= s) ? lds[t - s] : 0;
    __syncthreads();
    lds[t] += a;
    __syncthreads();
  }
  if (t < NB) bsums[t] = lds[t] - v;
}

__global__ __launch_bounds__(256) void scan3(int* __restrict__ offs,
    const int* __restrict__ bsums, int N, int E)
{
  int i = blockIdx.x * 256 + threadIdx.x;
  if (i < N) offs[i] += bsums[blockIdx.x];
  if (i == N) offs[N] = E;
}

__global__ __launch_bounds__(256) void k_fill(const int* __restrict__ ei,
    const int* __restrict__ offs, int* __restrict__ cursor,
    int2* __restrict__ csr, int E)
{
  int e = blockIdx.x * 256 + threadIdx.x;
  if (e >= E) return;
  int s = ei[e], d = ei[E + e];
  int pos = offs[d] + atomicAdd(&cursor[d], 1);
  csr[pos] = make_int2(s, e);
}

// ---------------- aggregation (wave per node, bf16 gather, pipelined) ------
__global__ __launch_bounds__(256) void k_agg(const unsigned short* __restrict__ h16,
    const int2* __restrict__ csr, const int* __restrict__ offs,
    const float4* __restrict__ es, unsigned short* __restrict__ agg, int N)
{
  const int c = threadIdx.x & 63;
  const int wid = blockIdx.x * 4 + (threadIdx.x >> 6);
  const int wstride = gridDim.x * 4;

  for (int n0 = wid; n0 < N; n0 += wstride) {
    const int n = __builtin_amdgcn_readfirstlane(n0);
    const int p0 = offs[n], p1 = offs[n + 1];

    float acc0 = 0.f, acc1 = 0.f, acc2 = 0.f, acc3 = 0.f;
    float den0 = 0.f, den1 = 0.f, den2 = 0.f, den3 = 0.f;

    float4 evA = make_float4(0.f, 0.f, 0.f, 0.f);
    float hsA = 0.f;
    if (p0 < p1) {
      int2 se = csr[p0];
      evA = es[se.y];
      hsA = bf2f(h16[(size_t)se.x * 64 + c]);
    }
    for (int p = p0; p < p1; ++p) {
      float4 evB = evA; float hsB = hsA;
      if (p + 1 < p1) {                       // prefetch next edge fully
        int2 se = csr[p + 1];                 // s_load (wave-uniform)
        evB = es[se.y];                       // s_load
        hsB = bf2f(h16[(size_t)se.x * 64 + c]);  // coalesced 128B gather
      }
      den0 += evA.x; den1 += evA.y; den2 += evA.z; den3 += evA.w;
      acc0 = fmaf(evA.x, hsA, acc0);
      acc1 = fmaf(evA.y, hsA, acc1);
      acc2 = fmaf(evA.z, hsA, acc2);
      acc3 = fmaf(evA.w, hsA, acc3);
      evA = evB; hsA = hsB;
    }
    ushort4 o;
    o.x = f2bf(acc0 / (den0 + 1e-8f));
    o.y = f2bf(acc1 / (den1 + 1e-8f));
    o.z = f2bf(acc2 / (den2 + 1e-8f));
    o.w = f2bf(acc3 / (den3 + 1e-8f));
    *(ushort4*)(agg + (size_t)n * 256 + c * 4) = o;   // coalesced b64
  }
}

// ---------------- proj + residual + LN + ReLU (lane = node) ----------------
__global__ __launch_bounds__(256) void k_proj(const unsigned short* __restrict__ agg,
    const float* __restrict__ x,
    const float* __restrict__ Pw, const float* __restrict__ Pb,
    const float* __restrict__ lg, const float* __restrict__ lb,
    float* __restrict__ out, int N)
{
  const int lane = threadIdx.x & 63;
  const int wv = threadIdx.x >> 6;
  const int n = (blockIdx.x * 4 + wv) * 64 + lane;
  const bool valid = (n < N);
  const int nc = valid ? n : (N - 1);

  float o[64];
  #pragma unroll
  for (int c = 0; c < 64; ++c) o[c] = Pb[c];          // uniform -> s_load

  const unsigned short* arow = agg + (size_t)nc * 256;

  for (int ch = 0; ch < 16; ++ch) {                   // 16 chunks x 16 k
    uint4 u0 = *(const uint4*)(arow + ch * 16);
    uint4 u1 = *(const uint4*)(arow + ch * 16 + 8);
    float a[16];
    unsigned int uu[8] = {u0.x, u0.y, u0.z, u0.w, u1.x, u1.y, u1.z, u1.w};
    #pragma unroll
    for (int i = 0; i < 8; ++i) {
      a[2 * i]     = __uint_as_float(uu[i] << 16);
      a[2 * i + 1] = __uint_as_float(uu[i] & 0xFFFF0000u);
    }
    #pragma unroll
    for (int kk = 0; kk < 16; ++kk) {
      const float* Pr = Pw + (size_t)(ch * 16 + kk) * 64;  // uniform row
      #pragma unroll
      for (int c = 0; c < 64; ++c)
        o[c] = fmaf(a[kk], Pr[c], o[c]);              // v_fmac v, s, v
    }
  }

  const float* xr = x + (size_t)nc * 64;
  #pragma unroll
  for (int c4 = 0; c4 < 16; ++c4) {
    float4 xv = *(const float4*)(xr + c4 * 4);
    o[c4 * 4 + 0] += xv.x; o[c4 * 4 + 1] += xv.y;
    o[c4 * 4 + 2] += xv.z; o[c4 * 4 + 3] += xv.w;
  }

  float r[32];
  #pragma unroll
  for (int i = 0; i < 32; ++i) r[i] = o[i] + o[i + 32];
  #pragma unroll
  for (int st = 16; st >= 1; st >>= 1) {
    #pragma unroll
    for (int i = 0; i < 16; ++i)
      if (i < st) r[i] += r[i + st];
  }
  const float mu = r[0] * 0.015625f;

  #pragma unroll
  for (int i = 0; i < 32; ++i) {
    float d0 = o[i] - mu, d1 = o[i + 32] - mu;
    r[i] = fmaf(d0, d0, d1 * d1);
  }
  #pragma unroll
  for (int st = 16; st >= 1; st >>= 1) {
    #pragma unroll
    for (int i = 0; i < 16; ++i)
      if (i < st) r[i] += r[i + st];
  }
  const float inv = rsqrtf(r[0] * 0.015625f + 1e-5f);

  if (valid) {
    float* outr = out + (size_t)n * 64;
    #pragma unroll
    for (int c4 = 0; c4 < 16; ++c4) {
      float4 y;
      y.x = fmaxf(fmaf(lg[c4*4+0] * (o[c4*4+0] - mu), inv, lb[c4*4+0]), 0.f);
      y.y = fmaxf(fmaf(lg[c4*4+1] * (o[c4*4+1] - mu), inv, lb[c4*4+1]), 0.f);
      y.z = fmaxf(fmaf(lg[c4*4+2] * (o[c4*4+2] - mu), inv, lb[c4*4+2]), 0.f);
      y.w = fmaxf(fmaf(lg[c4*4+3] * (o[c4*4+3] - mu), inv, lb[c4*4+3]), 0.f);
      *(float4*)(outr + c4 * 4) = y;
    }
  }
}

// ---------------------------------------------------------------------------
extern "C" void kernel_launch(void* const* d_in, const int* in_sizes, int n_in,
                              void* d_out, int out_size, void* d_ws, size_t ws_size,
                              hipStream_t stream)
{
  const float* x  = (const float*)d_in[0];
  const int*   ei = (const int*)d_in[1];
  const float* et = (const float*)d_in[2];
  const int*   ct = (const int*)d_in[3];
  const float* Ww = (const float*)d_in[4];
  const float* Wb = (const float*)d_in[5];
  const float* aw = (const float*)d_in[6];
  const float* ab = (const float*)d_in[7];
  const float* dr = (const float*)d_in[8];
  const float* Pw = (const float*)d_in[9];
  const float* Pb = (const float*)d_in[10];
  const float* lg = (const float*)d_in[11];
  const float* lb = (const float*)d_in[12];
  float* out = (float*)d_out;

  const int N = in_sizes[0] / 64;
  const int E = in_sizes[2];

  char* ws = (char*)d_ws;
  size_t off = 0;
  auto take = [&](size_t bytes) -> char* {
    char* p = ws + off;
    off = (off + bytes + 255) & ~(size_t)255;
    return p;
  };
  float*  h      = (float*)take((size_t)N * 64 * 4);
  unsigned short* h16 = (unsigned short*)take((size_t)N * 64 * 2);
  int*    deg    = (int*)take((size_t)N * 4 * 2);
  int*    cursor = deg + N;
  int*    offs   = (int*)take((size_t)(N + 1) * 4);
  int*    bsums  = (int*)take(512 * 4);
  int2*   csr    = (int2*)take((size_t)E * 8);
  float4* es     = (float4*)take((size_t)E * 16);
  unsigned short* agg = (unsigned short*)take((size_t)N * 256 * 2);
  float4* u      = (float4*)take((size_t)N * 16);
  float4* v      = (float4*)take((size_t)N * 16);

  hipMemsetAsync(deg, 0, (size_t)N * 8, stream);

  k_h<<<1024, 256, 0, stream>>>(x, Ww, Wb, h, h16, N);
  k_uv<<<(N + 15) / 16, 256, 0, stream>>>(h, aw, u, v, N);
  k_score<<<(E + 255) / 256, 256, 0, stream>>>(u, v, ei, et, ct, dr, ab, es, E);
  k_deg<<<(E + 255) / 256, 256, 0, stream>>>(ei, deg, E);
  const int NB = (N + 255) / 256;
  scan1<<<NB, 256, 0, stream>>>(deg, offs, bsums, N);
  scan2<<<1, 512, 0, stream>>>(bsums, NB);
  scan3<<<NB, 256, 0, stream>>>(offs, bsums, N, E);
  k_fill<<<(E + 255) / 256, 256, 0, stream>>>(ei, offs, cursor, csr, E);
  k_agg<<<2048, 256, 0, stream>>>(h16, csr, offs, es, agg, N);
  k_proj<<<(N + 255) / 256, 256, 0, stream>>>(agg, x, Pw, Pb, lg, lb, out, N);
}

// Round 4
// 378.139 us; speedup vs baseline: 1.7571x; 1.2247x over previous
//
#include <hip/hip_runtime.h>

// ---------------------------------------------------------------------------
// TemporalHeteroConv on MI355X.  N=100000 nodes, E=800000 edges, C=64, H=4.
// Pipeline:
//   k_hn     : lane = node. h row in registers via scalar-broadcast W
//              (s_load + v_fmac, NO LDS/shuffles -- r3's k_h was DS-issue
//              bound: 128 DS ops/node ~= 105us). Writes h16 (bf16) and the
//              fused u = h@a1, v = h@a2 tables. fp32 h never materialized.
//   k_score  : thread/edge: es[e] = exp(leakyrelu(u+v+b)*decay); fused deg
//              count (saves k_deg's 6.4MB edge re-read + launch).
//   scan1..3 / k_fill : CSR by destination
//   k_agg    : wave/node, bf16 h gather (128B/edge), prefetch pipelined;
//              agg rows in bf16.
//   k_proj   : lane = node; agg @ proj_w via scalar-broadcast P, in-register
//              residual + LayerNorm + ReLU.
// ---------------------------------------------------------------------------

__device__ __forceinline__ unsigned short f2bf(float f) {
  unsigned int u = __float_as_uint(f);
  u += 0x7FFFu + ((u >> 16) & 1u);          // RNE
  return (unsigned short)(u >> 16);
}
__device__ __forceinline__ float bf2f(unsigned short s) {
  return __uint_as_float(((unsigned int)s) << 16);
}

#define FMA4(P, S, R) { P.x = fmaf(S, R.x, P.x); P.y = fmaf(S, R.y, P.y); \
                        P.z = fmaf(S, R.z, P.z); P.w = fmaf(S, R.w, P.w); }

// ------- h/u/v producer: lane = node, scalar-broadcast W, no LDS ----------
__global__ __launch_bounds__(64) void k_hn(const float* __restrict__ x,
    const float* __restrict__ Ww, const float* __restrict__ Wb,
    const float* __restrict__ attn_w,
    unsigned short* __restrict__ h16, float4* __restrict__ u,
    float4* __restrict__ v, int N)
{
  const int n = blockIdx.x * 64 + threadIdx.x;
  const bool valid = (n < N);
  const int nc = valid ? n : (N - 1);

  float o[64];
  #pragma unroll
  for (int c = 0; c < 64; ++c) o[c] = Wb[c];          // uniform -> s_load

  const float* xr = x + (size_t)nc * 64;
  for (int ch = 0; ch < 16; ++ch) {                   // 16 chunks x 4 k
    float4 xv = *(const float4*)(xr + ch * 4);
    float a[4] = {xv.x, xv.y, xv.z, xv.w};
    #pragma unroll
    for (int kk = 0; kk < 4; ++kk) {
      const float* Wr = Ww + (size_t)(ch * 4 + kk) * 64;   // uniform row
      #pragma unroll
      for (int c = 0; c < 64; ++c)
        o[c] = fmaf(a[kk], Wr[c], o[c]);              // v_fmac v, s, v
    }
  }

  // fused u = h@a1, v = h@a2  (attn_w rows are wave-uniform)
  float4 uu = make_float4(0.f, 0.f, 0.f, 0.f);
  float4 vv = make_float4(0.f, 0.f, 0.f, 0.f);
  const float4* aw = (const float4*)attn_w;           // row c -> 4 heads
  #pragma unroll
  for (int c = 0; c < 64; ++c) {
    float4 r1 = aw[c];
    float4 r2 = aw[64 + c];
    FMA4(uu, o[c], r1);
    FMA4(vv, o[c], r2);
  }

  if (valid) {
    unsigned int* hr = (unsigned int*)(h16 + (size_t)n * 64);
    #pragma unroll
    for (int i = 0; i < 8; ++i) {                     // 8 x 16B packed stores
      uint4 w;
      w.x = (unsigned int)f2bf(o[i*8+0]) | ((unsigned int)f2bf(o[i*8+1]) << 16);
      w.y = (unsigned int)f2bf(o[i*8+2]) | ((unsigned int)f2bf(o[i*8+3]) << 16);
      w.z = (unsigned int)f2bf(o[i*8+4]) | ((unsigned int)f2bf(o[i*8+5]) << 16);
      w.w = (unsigned int)f2bf(o[i*8+6]) | ((unsigned int)f2bf(o[i*8+7]) << 16);
      *(uint4*)(hr + i * 4) = w;
    }
    u[n] = uu;
    v[n] = vv;
  }
}

// ---------------- per-edge exp-scores + degree count -----------------------
__global__ __launch_bounds__(256) void k_score(const float4* __restrict__ u,
    const float4* __restrict__ v,
    const int* __restrict__ ei, const float* __restrict__ et,
    const int* __restrict__ ctime, const float* __restrict__ drate,
    const float* __restrict__ attn_b, float4* __restrict__ es,
    int* __restrict__ deg, int E)
{
  int e = blockIdx.x * 256 + threadIdx.x;
  if (e >= E) return;
  const int src = ei[e];
  const int dst = ei[E + e];
  atomicAdd(&deg[dst], 1);
  const float4 us = u[src];
  const float4 vd = v[dst];
  const float4 ab = *(const float4*)attn_b;
  const float lam = log1pf(__expf(drate[0]));                 // softplus
  const float w = __expf(-lam * ((float)ctime[0] - et[e]));   // decay

  float4 o; float t;
  t = us.x + vd.x + ab.x; t = (t > 0.f ? t : 0.2f * t) * w; o.x = __expf(t);
  t = us.y + vd.y + ab.y; t = (t > 0.f ? t : 0.2f * t) * w; o.y = __expf(t);
  t = us.z + vd.z + ab.z; t = (t > 0.f ? t : 0.2f * t) * w; o.z = __expf(t);
  t = us.w + vd.w + ab.w; t = (t > 0.f ? t : 0.2f * t) * w; o.w = __expf(t);
  es[e] = o;
}

// ---------------- CSR build ----------------
__global__ __launch_bounds__(256) void scan1(const int* __restrict__ deg,
    int* __restrict__ offs, int* __restrict__ bsums, int N)
{
  int i = blockIdx.x * 256 + threadIdx.x;
  int lane = threadIdx.x & 63;
  int w = threadIdx.x >> 6;
  int v = (i < N) ? deg[i] : 0;
  int s = v;
  #pragma unroll
  for (int d = 1; d < 64; d <<= 1) {
    int t = __shfl_up(s, d, 64);
    if (lane >= d) s += t;
  }
  __shared__ int wsum[4];
  if (lane == 63) wsum[w] = s;
  __syncthreads();
  int add = 0;
  if (w > 0) add += wsum[0];
  if (w > 1) add += wsum[1];
  if (w > 2) add += wsum[2];
  if (i < N) offs[i] = s - v + add;
  if (threadIdx.x == 255) bsums[blockIdx.x] = wsum[0] + wsum[1] + wsum[2] + wsum[3];
}

__global__ __launch_bounds__(512) void scan2(int* bsums, int NB)
{
  __shared__ int lds[512];
  int t = threadIdx.x;
  int v = (t < NB) ? bsums[t] : 0;
  lds[t] = v;
  __syncthreads();
  for (int s = 1; s < 512; s <<= 1) {
    int a = (t >= s) ? lds[t - s] : 0;
    __syncthreads();
    lds[t] += a;
    __syncthreads();
  }
  if (t < NB) bsums[t] = lds[t] - v;
}

__global__ __launch_bounds__(256) void scan3(int* __restrict__ offs,
    const int* __restrict__ bsums, int N, int E)
{
  int i = blockIdx.x * 256 + threadIdx.x;
  if (i < N) offs[i] += bsums[blockIdx.x];
  if (i == N) offs[N] = E;
}

__global__ __launch_bounds__(256) void k_fill(const int* __restrict__ ei,
    const int* __restrict__ offs, int* __restrict__ cursor,
    int2* __restrict__ csr, int E)
{
  int e = blockIdx.x * 256 + threadIdx.x;
  if (e >= E) return;
  int s = ei[e], d = ei[E + e];
  int pos = offs[d] + atomicAdd(&cursor[d], 1);
  csr[pos] = make_int2(s, e);
}

// ---------------- aggregation (wave per node, bf16 gather, pipelined) ------
__global__ __launch_bounds__(256) void k_agg(const unsigned short* __restrict__ h16,
    const int2* __restrict__ csr, const int* __restrict__ offs,
    const float4* __restrict__ es, unsigned short* __restrict__ agg, int N)
{
  const int c = threadIdx.x & 63;
  const int wid = blockIdx.x * 4 + (threadIdx.x >> 6);
  const int wstride = gridDim.x * 4;

  for (int n0 = wid; n0 < N; n0 += wstride) {
    const int n = __builtin_amdgcn_readfirstlane(n0);
    const int p0 = offs[n], p1 = offs[n + 1];

    float acc0 = 0.f, acc1 = 0.f, acc2 = 0.f, acc3 = 0.f;
    float den0 = 0.f, den1 = 0.f, den2 = 0.f, den3 = 0.f;

    float4 evA = make_float4(0.f, 0.f, 0.f, 0.f);
    float hsA = 0.f;
    if (p0 < p1) {
      int2 se = csr[p0];
      evA = es[se.y];
      hsA = bf2f(h16[(size_t)se.x * 64 + c]);
    }
    for (int p = p0; p < p1; ++p) {
      float4 evB = evA; float hsB = hsA;
      if (p + 1 < p1) {                       // prefetch next edge fully
        int2 se = csr[p + 1];                 // s_load (wave-uniform)
        evB = es[se.y];                       // s_load
        hsB = bf2f(h16[(size_t)se.x * 64 + c]);  // coalesced 128B gather
      }
      den0 += evA.x; den1 += evA.y; den2 += evA.z; den3 += evA.w;
      acc0 = fmaf(evA.x, hsA, acc0);
      acc1 = fmaf(evA.y, hsA, acc1);
      acc2 = fmaf(evA.z, hsA, acc2);
      acc3 = fmaf(evA.w, hsA, acc3);
      evA = evB; hsA = hsB;
    }
    ushort4 o;
    o.x = f2bf(acc0 / (den0 + 1e-8f));
    o.y = f2bf(acc1 / (den1 + 1e-8f));
    o.z = f2bf(acc2 / (den2 + 1e-8f));
    o.w = f2bf(acc3 / (den3 + 1e-8f));
    *(ushort4*)(agg + (size_t)n * 256 + c * 4) = o;   // coalesced b64
  }
}

// ---------------- proj + residual + LN + ReLU (lane = node) ----------------
__global__ __launch_bounds__(256) void k_proj(const unsigned short* __restrict__ agg,
    const float* __restrict__ x,
    const float* __restrict__ Pw, const float* __restrict__ Pb,
    const float* __restrict__ lg, const float* __restrict__ lb,
    float* __restrict__ out, int N)
{
  const int lane = threadIdx.x & 63;
  const int wv = threadIdx.x >> 6;
  const int n = (blockIdx.x * 4 + wv) * 64 + lane;
  const bool valid = (n < N);
  const int nc = valid ? n : (N - 1);

  float o[64];
  #pragma unroll
  for (int c = 0; c < 64; ++c) o[c] = Pb[c];          // uniform -> s_load

  const unsigned short* arow = agg + (size_t)nc * 256;

  for (int ch = 0; ch < 16; ++ch) {                   // 16 chunks x 16 k
    uint4 u0 = *(const uint4*)(arow + ch * 16);
    uint4 u1 = *(const uint4*)(arow + ch * 16 + 8);
    float a[16];
    unsigned int uu[8] = {u0.x, u0.y, u0.z, u0.w, u1.x, u1.y, u1.z, u1.w};
    #pragma unroll
    for (int i = 0; i < 8; ++i) {
      a[2 * i]     = __uint_as_float(uu[i] << 16);
      a[2 * i + 1] = __uint_as_float(uu[i] & 0xFFFF0000u);
    }
    #pragma unroll
    for (int kk = 0; kk < 16; ++kk) {
      const float* Pr = Pw + (size_t)(ch * 16 + kk) * 64;  // uniform row
      #pragma unroll
      for (int c = 0; c < 64; ++c)
        o[c] = fmaf(a[kk], Pr[c], o[c]);              // v_fmac v, s, v
    }
  }

  const float* xr = x + (size_t)nc * 64;
  #pragma unroll
  for (int c4 = 0; c4 < 16; ++c4) {
    float4 xv = *(const float4*)(xr + c4 * 4);
    o[c4 * 4 + 0] += xv.x; o[c4 * 4 + 1] += xv.y;
    o[c4 * 4 + 2] += xv.z; o[c4 * 4 + 3] += xv.w;
  }

  float r[32];
  #pragma unroll
  for (int i = 0; i < 32; ++i) r[i] = o[i] + o[i + 32];
  #pragma unroll
  for (int st = 16; st >= 1; st >>= 1) {
    #pragma unroll
    for (int i = 0; i < 16; ++i)
      if (i < st) r[i] += r[i + st];
  }
  const float mu = r[0] * 0.015625f;

  #pragma unroll
  for (int i = 0; i < 32; ++i) {
    float d0 = o[i] - mu, d1 = o[i + 32] - mu;
    r[i] = fmaf(d0, d0, d1 * d1);
  }
  #pragma unroll
  for (int st = 16; st >= 1; st >>= 1) {
    #pragma unroll
    for (int i = 0; i < 16; ++i)
      if (i < st) r[i] += r[i + st];
  }
  const float inv = rsqrtf(r[0] * 0.015625f + 1e-5f);

  if (valid) {
    float* outr = out + (size_t)n * 64;
    #pragma unroll
    for (int c4 = 0; c4 < 16; ++c4) {
      float4 y;
      y.x = fmaxf(fmaf(lg[c4*4+0] * (o[c4*4+0] - mu), inv, lb[c4*4+0]), 0.f);
      y.y = fmaxf(fmaf(lg[c4*4+1] * (o[c4*4+1] - mu), inv, lb[c4*4+1]), 0.f);
      y.z = fmaxf(fmaf(lg[c4*4+2] * (o[c4*4+2] - mu), inv, lb[c4*4+2]), 0.f);
      y.w = fmaxf(fmaf(lg[c4*4+3] * (o[c4*4+3] - mu), inv, lb[c4*4+3]), 0.f);
      *(float4*)(outr + c4 * 4) = y;
    }
  }
}

// ---------------------------------------------------------------------------
extern "C" void kernel_launch(void* const* d_in, const int* in_sizes, int n_in,
                              void* d_out, int out_size, void* d_ws, size_t ws_size,
                              hipStream_t stream)
{
  const float* x  = (const float*)d_in[0];
  const int*   ei = (const int*)d_in[1];
  const float* et = (const float*)d_in[2];
  const int*   ct = (const int*)d_in[3];
  const float* Ww = (const float*)d_in[4];
  const float* Wb = (const float*)d_in[5];
  const float* aw = (const float*)d_in[6];
  const float* ab = (const float*)d_in[7];
  const float* dr = (const float*)d_in[8];
  const float* Pw = (const float*)d_in[9];
  const float* Pb = (const float*)d_in[10];
  const float* lg = (const float*)d_in[11];
  const float* lb = (const float*)d_in[12];
  float* out = (float*)d_out;

  const int N = in_sizes[0] / 64;
  const int E = in_sizes[2];

  char* ws = (char*)d_ws;
  size_t off = 0;
  auto take = [&](size_t bytes) -> char* {
    char* p = ws + off;
    off = (off + bytes + 255) & ~(size_t)255;
    return p;
  };
  unsigned short* h16 = (unsigned short*)take((size_t)N * 64 * 2);
  int*    deg    = (int*)take((size_t)N * 4 * 2);
  int*    cursor = deg + N;
  int*    offs   = (int*)take((size_t)(N + 1) * 4);
  int*    bsums  = (int*)take(512 * 4);
  int2*   csr    = (int2*)take((size_t)E * 8);
  float4* es     = (float4*)take((size_t)E * 16);
  unsigned short* agg = (unsigned short*)take((size_t)N * 256 * 2);
  float4* u      = (float4*)take((size_t)N * 16);
  float4* v      = (float4*)take((size_t)N * 16);

  hipMemsetAsync(deg, 0, (size_t)N * 8, stream);

  k_hn<<<(N + 63) / 64, 64, 0, stream>>>(x, Ww, Wb, aw, h16, u, v, N);
  k_score<<<(E + 255) / 256, 256, 0, stream>>>(u, v, ei, et, ct, dr, ab, es, deg, E);
  const int NB = (N + 255) / 256;
  scan1<<<NB, 256, 0, stream>>>(deg, offs, bsums, N);
  scan2<<<1, 512, 0, stream>>>(bsums, NB);
  scan3<<<NB, 256, 0, stream>>>(offs, bsums, N, E);
  k_fill<<<(E + 255) / 256, 256, 0, stream>>>(ei, offs, cursor, csr, E);
  k_agg<<<2048, 256, 0, stream>>>(h16, csr, offs, es, agg, N);
  k_proj<<<(N + 255) / 256, 256, 0, stream>>>(agg, x, Pw, Pb, lg, lb, out, N);
}

// Round 5
// 315.260 us; speedup vs baseline: 2.1075x; 1.1995x over previous
//
#include <hip/hip_runtime.h>

// ---------------------------------------------------------------------------
// TemporalHeteroConv on MI355X.  N=100000 nodes, E=800000 edges, C=64, H=4.
// Pipeline:
//   k_hn     : lane = node. h row in registers via scalar-broadcast W;
//              writes h16 (bf16) + fused u/v attention tables.
//   k_score  : thread/edge: es[e] = exp(leakyrelu(u+v+b)*decay); fused deg.
//   scan1..3 / k_fill : CSR by destination
//   k_agg    : wave/node, bf16 h gather (128B/edge); edges processed in
//              groups of 4 with next-group prefetch (8 loads in flight --
//              r4 version was depth-1, load-latency-bound).
//   k_pw     : pack Pw into bf16 MFMA B-fragment order (32 KB, L2-resident).
//   k_projm  : MFMA proj GEMM agg(N,256)@Pw(256,64), wave per 16-node tile,
//              LN+residual+ReLU epilogue in C/D layout (2 shuffles/node).
//              [r4 k_proj was lane=node: 391 blocks, strided accesses,
//               latency-bound at 98us]
// ---------------------------------------------------------------------------

typedef __attribute__((ext_vector_type(8))) short bf16x8;
typedef __attribute__((ext_vector_type(4))) float f32x4;

__device__ __forceinline__ unsigned short f2bf(float f) {
  unsigned int u = __float_as_uint(f);
  u += 0x7FFFu + ((u >> 16) & 1u);          // RNE
  return (unsigned short)(u >> 16);
}
__device__ __forceinline__ float bf2f(unsigned short s) {
  return __uint_as_float(((unsigned int)s) << 16);
}

#define FMA4(P, S, R) { P.x = fmaf(S, R.x, P.x); P.y = fmaf(S, R.y, P.y); \
                        P.z = fmaf(S, R.z, P.z); P.w = fmaf(S, R.w, P.w); }

// ------- h/u/v producer: lane = node, scalar-broadcast W, no LDS ----------
__global__ __launch_bounds__(64) void k_hn(const float* __restrict__ x,
    const float* __restrict__ Ww, const float* __restrict__ Wb,
    const float* __restrict__ attn_w,
    unsigned short* __restrict__ h16, float4* __restrict__ u,
    float4* __restrict__ v, int N)
{
  const int n = blockIdx.x * 64 + threadIdx.x;
  const bool valid = (n < N);
  const int nc = valid ? n : (N - 1);

  float o[64];
  #pragma unroll
  for (int c = 0; c < 64; ++c) o[c] = Wb[c];

  const float* xr = x + (size_t)nc * 64;
  for (int ch = 0; ch < 16; ++ch) {
    float4 xv = *(const float4*)(xr + ch * 4);
    float a[4] = {xv.x, xv.y, xv.z, xv.w};
    #pragma unroll
    for (int kk = 0; kk < 4; ++kk) {
      const float* Wr = Ww + (size_t)(ch * 4 + kk) * 64;
      #pragma unroll
      for (int c = 0; c < 64; ++c)
        o[c] = fmaf(a[kk], Wr[c], o[c]);
    }
  }

  float4 uu = make_float4(0.f, 0.f, 0.f, 0.f);
  float4 vv = make_float4(0.f, 0.f, 0.f, 0.f);
  const float4* aw = (const float4*)attn_w;
  #pragma unroll
  for (int c = 0; c < 64; ++c) {
    float4 r1 = aw[c];
    float4 r2 = aw[64 + c];
    FMA4(uu, o[c], r1);
    FMA4(vv, o[c], r2);
  }

  if (valid) {
    unsigned int* hr = (unsigned int*)(h16 + (size_t)n * 64);
    #pragma unroll
    for (int i = 0; i < 8; ++i) {
      uint4 w;
      w.x = (unsigned int)f2bf(o[i*8+0]) | ((unsigned int)f2bf(o[i*8+1]) << 16);
      w.y = (unsigned int)f2bf(o[i*8+2]) | ((unsigned int)f2bf(o[i*8+3]) << 16);
      w.z = (unsigned int)f2bf(o[i*8+4]) | ((unsigned int)f2bf(o[i*8+5]) << 16);
      w.w = (unsigned int)f2bf(o[i*8+6]) | ((unsigned int)f2bf(o[i*8+7]) << 16);
      *(uint4*)(hr + i * 4) = w;
    }
    u[n] = uu;
    v[n] = vv;
  }
}

// ---------------- per-edge exp-scores + degree count -----------------------
__global__ __launch_bounds__(256) void k_score(const float4* __restrict__ u,
    const float4* __restrict__ v,
    const int* __restrict__ ei, const float* __restrict__ et,
    const int* __restrict__ ctime, const float* __restrict__ drate,
    const float* __restrict__ attn_b, float4* __restrict__ es,
    int* __restrict__ deg, int E)
{
  int e = blockIdx.x * 256 + threadIdx.x;
  if (e >= E) return;
  const int src = ei[e];
  const int dst = ei[E + e];
  atomicAdd(&deg[dst], 1);
  const float4 us = u[src];
  const float4 vd = v[dst];
  const float4 ab = *(const float4*)attn_b;
  const float lam = log1pf(__expf(drate[0]));
  const float w = __expf(-lam * ((float)ctime[0] - et[e]));

  float4 o; float t;
  t = us.x + vd.x + ab.x; t = (t > 0.f ? t : 0.2f * t) * w; o.x = __expf(t);
  t = us.y + vd.y + ab.y; t = (t > 0.f ? t : 0.2f * t) * w; o.y = __expf(t);
  t = us.z + vd.z + ab.z; t = (t > 0.f ? t : 0.2f * t) * w; o.z = __expf(t);
  t = us.w + vd.w + ab.w; t = (t > 0.f ? t : 0.2f * t) * w; o.w = __expf(t);
  es[e] = o;
}

// ---------------- CSR build ----------------
__global__ __launch_bounds__(256) void scan1(const int* __restrict__ deg,
    int* __restrict__ offs, int* __restrict__ bsums, int N)
{
  int i = blockIdx.x * 256 + threadIdx.x;
  int lane = threadIdx.x & 63;
  int w = threadIdx.x >> 6;
  int v = (i < N) ? deg[i] : 0;
  int s = v;
  #pragma unroll
  for (int d = 1; d < 64; d <<= 1) {
    int t = __shfl_up(s, d, 64);
    if (lane >= d) s += t;
  }
  __shared__ int wsum[4];
  if (lane == 63) wsum[w] = s;
  __syncthreads();
  int add = 0;
  if (w > 0) add += wsum[0];
  if (w > 1) add += wsum[1];
  if (w > 2) add += wsum[2];
  if (i < N) offs[i] = s - v + add;
  if (threadIdx.x == 255) bsums[blockIdx.x] = wsum[0] + wsum[1] + wsum[2] + wsum[3];
}

__global__ __launch_bounds__(512) void scan2(int* bsums, int NB)
{
  __shared__ int lds[512];
  int t = threadIdx.x;
  int v = (t < NB) ? bsums[t] : 0;
  lds[t] = v;
  __syncthreads();
  for (int s = 1; s < 512; s <<= 1) {
    int a = (t >= s) ? lds[t - s] : 0;
    __syncthreads();
    lds[t] += a;
    __syncthreads();
  }
  if (t < NB) bsums[t] = lds[t] - v;
}

__global__ __launch_bounds__(256) void scan3(int* __restrict__ offs,
    const int* __restrict__ bsums, int N, int E)
{
  int i = blockIdx.x * 256 + threadIdx.x;
  if (i < N) offs[i] += bsums[blockIdx.x];
  if (i == N) offs[N] = E;
}

__global__ __launch_bounds__(256) void k_fill(const int* __restrict__ ei,
    const int* __restrict__ offs, int* __restrict__ cursor,
    int2* __restrict__ csr, int E)
{
  int e = blockIdx.x * 256 + threadIdx.x;
  if (e >= E) return;
  int s = ei[e], d = ei[E + e];
  int pos = offs[d] + atomicAdd(&cursor[d], 1);
  csr[pos] = make_int2(s, e);
}

// ------- aggregation: wave/node, 4-edge groups, next-group prefetch -------
#define AGG_LOAD(P, E0, E1, E2, E3, G0, G1, G2, G3, M1, M2, M3) do {        \
    int _q1 = (P) + 1 < p1 ? (P) + 1 : p1 - 1;                              \
    int _q2 = (P) + 2 < p1 ? (P) + 2 : p1 - 1;                              \
    int _q3 = (P) + 3 < p1 ? (P) + 3 : p1 - 1;                              \
    int2 _a0 = csr[P], _a1 = csr[_q1], _a2 = csr[_q2], _a3 = csr[_q3];      \
    E0 = es[_a0.y]; E1 = es[_a1.y]; E2 = es[_a2.y]; E3 = es[_a3.y];         \
    G0 = bf2f(h16[(size_t)_a0.x * 64 + c]);                                 \
    G1 = bf2f(h16[(size_t)_a1.x * 64 + c]);                                 \
    G2 = bf2f(h16[(size_t)_a2.x * 64 + c]);                                 \
    G3 = bf2f(h16[(size_t)_a3.x * 64 + c]);                                 \
    M1 = (P) + 1 < p1 ? 1.f : 0.f;                                          \
    M2 = (P) + 2 < p1 ? 1.f : 0.f;                                          \
    M3 = (P) + 3 < p1 ? 1.f : 0.f;                                          \
  } while (0)

__global__ __launch_bounds__(256) void k_agg(const unsigned short* __restrict__ h16,
    const int2* __restrict__ csr, const int* __restrict__ offs,
    const float4* __restrict__ es, unsigned short* __restrict__ agg, int N)
{
  const int c = threadIdx.x & 63;
  const int wid = blockIdx.x * 4 + (threadIdx.x >> 6);
  const int wstride = gridDim.x * 4;

  for (int n0 = wid; n0 < N; n0 += wstride) {
    const int n = __builtin_amdgcn_readfirstlane(n0);
    const int p0 = offs[n], p1 = offs[n + 1];

    float acc0 = 0.f, acc1 = 0.f, acc2 = 0.f, acc3 = 0.f;
    float den0 = 0.f, den1 = 0.f, den2 = 0.f, den3 = 0.f;

    float4 eA0, eA1, eA2, eA3;
    float gA0, gA1, gA2, gA3, mA1, mA2, mA3;
    if (p0 < p1) AGG_LOAD(p0, eA0, eA1, eA2, eA3, gA0, gA1, gA2, gA3, mA1, mA2, mA3);

    for (int p = p0; p < p1; p += 4) {
      float4 eB0, eB1, eB2, eB3;
      float gB0, gB1, gB2, gB3, mB1, mB2, mB3;
      if (p + 4 < p1)
        AGG_LOAD(p + 4, eB0, eB1, eB2, eB3, gB0, gB1, gB2, gB3, mB1, mB2, mB3);

      eA1.x *= mA1; eA1.y *= mA1; eA1.z *= mA1; eA1.w *= mA1;
      eA2.x *= mA2; eA2.y *= mA2; eA2.z *= mA2; eA2.w *= mA2;
      eA3.x *= mA3; eA3.y *= mA3; eA3.z *= mA3; eA3.w *= mA3;
      den0 += (eA0.x + eA1.x) + (eA2.x + eA3.x);
      den1 += (eA0.y + eA1.y) + (eA2.y + eA3.y);
      den2 += (eA0.z + eA1.z) + (eA2.z + eA3.z);
      den3 += (eA0.w + eA1.w) + (eA2.w + eA3.w);
      acc0 = fmaf(eA0.x, gA0, fmaf(eA1.x, gA1, fmaf(eA2.x, gA2, fmaf(eA3.x, gA3, acc0))));
      acc1 = fmaf(eA0.y, gA0, fmaf(eA1.y, gA1, fmaf(eA2.y, gA2, fmaf(eA3.y, gA3, acc1))));
      acc2 = fmaf(eA0.z, gA0, fmaf(eA1.z, gA1, fmaf(eA2.z, gA2, fmaf(eA3.z, gA3, acc2))));
      acc3 = fmaf(eA0.w, gA0, fmaf(eA1.w, gA1, fmaf(eA2.w, gA2, fmaf(eA3.w, gA3, acc3))));

      if (p + 4 < p1) {
        eA0 = eB0; eA1 = eB1; eA2 = eB2; eA3 = eB3;
        gA0 = gB0; gA1 = gB1; gA2 = gB2; gA3 = gB3;
        mA1 = mB1; mA2 = mB2; mA3 = mB3;
      }
    }
    ushort4 o;
    o.x = f2bf(acc0 / (den0 + 1e-8f));
    o.y = f2bf(acc1 / (den1 + 1e-8f));
    o.z = f2bf(acc2 / (den2 + 1e-8f));
    o.w = f2bf(acc3 / (den3 + 1e-8f));
    *(ushort4*)(agg + (size_t)n * 256 + c * 4) = o;
  }
}

// ------- pack Pw (256x64 fp32) into bf16 MFMA B-fragment order ------------
// Bf[((ks*4+cb)*64 + lane)*8 + j] = bf16( Pw[(ks*32 + (lane>>4)*8 + j)*64
//                                           + cb*16 + (lane&15)] )
__global__ __launch_bounds__(256) void k_pw(const float* __restrict__ Pw,
    unsigned short* __restrict__ Bf)
{
  int i = blockIdx.x * 256 + threadIdx.x;   // 0..16383
  int j    = i & 7;
  int lane = (i >> 3) & 63;
  int cb   = (i >> 9) & 3;
  int ks   = i >> 11;
  int k    = ks * 32 + (lane >> 4) * 8 + j;
  int colg = cb * 16 + (lane & 15);
  Bf[i] = f2bf(Pw[(size_t)k * 64 + colg]);
}

// ------- proj GEMM via MFMA + fused residual/LN/ReLU epilogue -------------
__global__ __launch_bounds__(256) void k_projm(const unsigned short* __restrict__ agg,
    const unsigned short* __restrict__ Bf, const float* __restrict__ x,
    const float* __restrict__ Pb,
    const float* __restrict__ lg, const float* __restrict__ lb,
    float* __restrict__ out, int N)
{
  const int lane = threadIdx.x & 63;
  const int wv = threadIdx.x >> 6;
  const int nt = blockIdx.x * 4 + wv;           // 16-node tile index
  if (nt * 16 >= N) return;
  const int col  = lane & 15;
  const int quad = lane >> 4;
  const int base = nt * 16;

  // A: agg rows, m = lane&15, k = ks*32 + quad*8 + j
  int na = base + col; if (na >= N) na = N - 1;
  const unsigned short* aptr = agg + (size_t)na * 256 + quad * 8;

  f32x4 acc0 = {0.f, 0.f, 0.f, 0.f};
  f32x4 acc1 = {0.f, 0.f, 0.f, 0.f};
  f32x4 acc2 = {0.f, 0.f, 0.f, 0.f};
  f32x4 acc3 = {0.f, 0.f, 0.f, 0.f};

  #pragma unroll
  for (int ks = 0; ks < 8; ++ks) {
    bf16x8 av = *(const bf16x8*)(aptr + ks * 32);
    bf16x8 b0 = *(const bf16x8*)(Bf + ((size_t)(ks * 4 + 0) * 64 + lane) * 8);
    bf16x8 b1 = *(const bf16x8*)(Bf + ((size_t)(ks * 4 + 1) * 64 + lane) * 8);
    bf16x8 b2 = *(const bf16x8*)(Bf + ((size_t)(ks * 4 + 2) * 64 + lane) * 8);
    bf16x8 b3 = *(const bf16x8*)(Bf + ((size_t)(ks * 4 + 3) * 64 + lane) * 8);
    acc0 = __builtin_amdgcn_mfma_f32_16x16x32_bf16(av, b0, acc0, 0, 0, 0);
    acc1 = __builtin_amdgcn_mfma_f32_16x16x32_bf16(av, b1, acc1, 0, 0, 0);
    acc2 = __builtin_amdgcn_mfma_f32_16x16x32_bf16(av, b2, acc2, 0, 0, 0);
    acc3 = __builtin_amdgcn_mfma_f32_16x16x32_bf16(av, b3, acc3, 0, 0, 0);
  }

  // C/D layout: node = base + quad*4 + reg, out-col = cb*16 + col
  const float pb0 = Pb[col], pb1 = Pb[16 + col], pb2 = Pb[32 + col], pb3 = Pb[48 + col];
  float v[4][4];                                 // [cb][reg]
  #pragma unroll
  for (int r = 0; r < 4; ++r) {
    int node = base + quad * 4 + r; if (node >= N) node = N - 1;
    const float* xr = x + (size_t)node * 64;
    v[0][r] = acc0[r] + pb0 + xr[col];
    v[1][r] = acc1[r] + pb1 + xr[16 + col];
    v[2][r] = acc2[r] + pb2 + xr[32 + col];
    v[3][r] = acc3[r] + pb3 + xr[48 + col];
  }

  float mu[4], inv[4];
  #pragma unroll
  for (int r = 0; r < 4; ++r) {
    float s = (v[0][r] + v[1][r]) + (v[2][r] + v[3][r]);
    s += __shfl_xor(s, 1, 64); s += __shfl_xor(s, 2, 64);
    s += __shfl_xor(s, 4, 64); s += __shfl_xor(s, 8, 64);
    mu[r] = s * 0.015625f;
  }
  #pragma unroll
  for (int r = 0; r < 4; ++r) {
    float d0 = v[0][r] - mu[r], d1 = v[1][r] - mu[r];
    float d2 = v[2][r] - mu[r], d3 = v[3][r] - mu[r];
    float s = fmaf(d0, d0, d1 * d1) + fmaf(d2, d2, d3 * d3);
    s += __shfl_xor(s, 1, 64); s += __shfl_xor(s, 2, 64);
    s += __shfl_xor(s, 4, 64); s += __shfl_xor(s, 8, 64);
    inv[r] = rsqrtf(s * 0.015625f + 1e-5f);
  }

  const float lg0 = lg[col], lg1 = lg[16 + col], lg2 = lg[32 + col], lg3 = lg[48 + col];
  const float lb0 = lb[col], lb1 = lb[16 + col], lb2 = lb[32 + col], lb3 = lb[48 + col];
  #pragma unroll
  for (int r = 0; r < 4; ++r) {
    int node = base + quad * 4 + r;
    if (node < N) {
      float* orow = out + (size_t)node * 64;
      orow[col]      = fmaxf(fmaf(lg0 * (v[0][r] - mu[r]), inv[r], lb0), 0.f);
      orow[16 + col] = fmaxf(fmaf(lg1 * (v[1][r] - mu[r]), inv[r], lb1), 0.f);
      orow[32 + col] = fmaxf(fmaf(lg2 * (v[2][r] - mu[r]), inv[r], lb2), 0.f);
      orow[48 + col] = fmaxf(fmaf(lg3 * (v[3][r] - mu[r]), inv[r], lb3), 0.f);
    }
  }
}

// ---------------------------------------------------------------------------
extern "C" void kernel_launch(void* const* d_in, const int* in_sizes, int n_in,
                              void* d_out, int out_size, void* d_ws, size_t ws_size,
                              hipStream_t stream)
{
  const float* x  = (const float*)d_in[0];
  const int*   ei = (const int*)d_in[1];
  const float* et = (const float*)d_in[2];
  const int*   ct = (const int*)d_in[3];
  const float* Ww = (const float*)d_in[4];
  const float* Wb = (const float*)d_in[5];
  const float* aw = (const float*)d_in[6];
  const float* ab = (const float*)d_in[7];
  const float* dr = (const float*)d_in[8];
  const float* Pw = (const float*)d_in[9];
  const float* Pb = (const float*)d_in[10];
  const float* lg = (const float*)d_in[11];
  const float* lb = (const float*)d_in[12];
  float* out = (float*)d_out;

  const int N = in_sizes[0] / 64;
  const int E = in_sizes[2];

  char* ws = (char*)d_ws;
  size_t off = 0;
  auto take = [&](size_t bytes) -> char* {
    char* p = ws + off;
    off = (off + bytes + 255) & ~(size_t)255;
    return p;
  };
  unsigned short* h16 = (unsigned short*)take((size_t)N * 64 * 2);
  int*    deg    = (int*)take((size_t)N * 4 * 2);
  int*    cursor = deg + N;
  int*    offs   = (int*)take((size_t)(N + 1) * 4);
  int*    bsums  = (int*)take(512 * 4);
  int2*   csr    = (int2*)take((size_t)E * 8);
  float4* es     = (float4*)take((size_t)E * 16);
  unsigned short* agg = (unsigned short*)take((size_t)N * 256 * 2);
  float4* u      = (float4*)take((size_t)N * 16);
  float4* v      = (float4*)take((size_t)N * 16);
  unsigned short* Bf = (unsigned short*)take(16384 * 2);

  hipMemsetAsync(deg, 0, (size_t)N * 8, stream);

  k_pw<<<64, 256, 0, stream>>>(Pw, Bf);
  k_hn<<<(N + 63) / 64, 64, 0, stream>>>(x, Ww, Wb, aw, h16, u, v, N);
  k_score<<<(E + 255) / 256, 256, 0, stream>>>(u, v, ei, et, ct, dr, ab, es, deg, E);
  const int NB = (N + 255) / 256;
  scan1<<<NB, 256, 0, stream>>>(deg, offs, bsums, N);
  scan2<<<1, 512, 0, stream>>>(bsums, NB);
  scan3<<<NB, 256, 0, stream>>>(offs, bsums, N, E);
  k_fill<<<(E + 255) / 256, 256, 0, stream>>>(ei, offs, cursor, csr, E);
  k_agg<<<2048, 256, 0, stream>>>(h16, csr, offs, es, agg, N);
  const int NT = (N + 15) / 16;
  k_projm<<<(NT + 3) / 4, 256, 0, stream>>>(agg, Bf, x, Pb, lg, lb, out, N);
}

// Round 6
// 281.527 us; speedup vs baseline: 2.3600x; 1.1198x over previous
//
#include <hip/hip_runtime.h>

// ---------------------------------------------------------------------------
// TemporalHeteroConv on MI355X.  N=100000 nodes, E=800000 edges, C=64, H=4.
// Pipeline:
//   k_hn     : lane = node. h row in registers via scalar-broadcast W;
//              writes h16 (bf16) + fused u/v attention tables.
//   k_score  : thread/edge: est[e] = exp(leakyrelu(u+v+b)*decay);
//              rank[e] = atomicAdd(deg[dst]) (fused degree count).
//   scan1/2  : exclusive scan of deg (block-local + block sums; bsums[i>>8]
//              folded into consumers -- scan3 eliminated).
//   k_fill   : scatter src AND es VALUE into CSR slot offs+rank (no atomics).
//              [r5: k_agg's indirect es[se.y] was ~1/3 of its VALU; CSR-ordered
//               es makes the k_agg es stream sequential wave-uniform s_loads]
//   k_agg    : wave/node, maskless pipelined groups-of-4 + scalar tail,
//              bf16 h gather (128B/edge); agg rows in bf16.
//   k_pw     : pack Pw into bf16 MFMA B-fragment order (32 KB, L2-resident).
//   k_projm  : MFMA proj GEMM agg(N,256)@Pw(256,64), wave per 16-node tile,
//              LN+residual+ReLU epilogue in C/D layout.
// ---------------------------------------------------------------------------

typedef __attribute__((ext_vector_type(8))) short bf16x8;
typedef __attribute__((ext_vector_type(4))) float f32x4;

__device__ __forceinline__ unsigned short f2bf(float f) {
  unsigned int u = __float_as_uint(f);
  u += 0x7FFFu + ((u >> 16) & 1u);          // RNE
  return (unsigned short)(u >> 16);
}
__device__ __forceinline__ float bf2f(unsigned short s) {
  return __uint_as_float(((unsigned int)s) << 16);
}

#define FMA4(P, S, R) { P.x = fmaf(S, R.x, P.x); P.y = fmaf(S, R.y, P.y); \
                        P.z = fmaf(S, R.z, P.z); P.w = fmaf(S, R.w, P.w); }

// ------- h/u/v producer: lane = node, scalar-broadcast W, no LDS ----------
__global__ __launch_bounds__(64) void k_hn(const float* __restrict__ x,
    const float* __restrict__ Ww, const float* __restrict__ Wb,
    const float* __restrict__ attn_w,
    unsigned short* __restrict__ h16, float4* __restrict__ u,
    float4* __restrict__ v, int N)
{
  const int n = blockIdx.x * 64 + threadIdx.x;
  const bool valid = (n < N);
  const int nc = valid ? n : (N - 1);

  float o[64];
  #pragma unroll
  for (int c = 0; c < 64; ++c) o[c] = Wb[c];

  const float* xr = x + (size_t)nc * 64;
  for (int ch = 0; ch < 16; ++ch) {
    float4 xv = *(const float4*)(xr + ch * 4);
    float a[4] = {xv.x, xv.y, xv.z, xv.w};
    #pragma unroll
    for (int kk = 0; kk < 4; ++kk) {
      const float* Wr = Ww + (size_t)(ch * 4 + kk) * 64;
      #pragma unroll
      for (int c = 0; c < 64; ++c)
        o[c] = fmaf(a[kk], Wr[c], o[c]);
    }
  }

  float4 uu = make_float4(0.f, 0.f, 0.f, 0.f);
  float4 vv = make_float4(0.f, 0.f, 0.f, 0.f);
  const float4* aw = (const float4*)attn_w;
  #pragma unroll
  for (int c = 0; c < 64; ++c) {
    float4 r1 = aw[c];
    float4 r2 = aw[64 + c];
    FMA4(uu, o[c], r1);
    FMA4(vv, o[c], r2);
  }

  if (valid) {
    unsigned int* hr = (unsigned int*)(h16 + (size_t)n * 64);
    #pragma unroll
    for (int i = 0; i < 8; ++i) {
      uint4 w;
      w.x = (unsigned int)f2bf(o[i*8+0]) | ((unsigned int)f2bf(o[i*8+1]) << 16);
      w.y = (unsigned int)f2bf(o[i*8+2]) | ((unsigned int)f2bf(o[i*8+3]) << 16);
      w.z = (unsigned int)f2bf(o[i*8+4]) | ((unsigned int)f2bf(o[i*8+5]) << 16);
      w.w = (unsigned int)f2bf(o[i*8+6]) | ((unsigned int)f2bf(o[i*8+7]) << 16);
      *(uint4*)(hr + i * 4) = w;
    }
    u[n] = uu;
    v[n] = vv;
  }
}

// -------- per-edge exp-scores + degree count + slot rank -------------------
__global__ __launch_bounds__(256) void k_score(const float4* __restrict__ u,
    const float4* __restrict__ v,
    const int* __restrict__ ei, const float* __restrict__ et,
    const int* __restrict__ ctime, const float* __restrict__ drate,
    const float* __restrict__ attn_b, float4* __restrict__ est,
    int* __restrict__ deg, int* __restrict__ rank, int E)
{
  int e = blockIdx.x * 256 + threadIdx.x;
  if (e >= E) return;
  const int src = ei[e];
  const int dst = ei[E + e];
  rank[e] = atomicAdd(&deg[dst], 1);
  const float4 us = u[src];
  const float4 vd = v[dst];
  const float4 ab = *(const float4*)attn_b;
  const float lam = log1pf(__expf(drate[0]));
  const float w = __expf(-lam * ((float)ctime[0] - et[e]));

  float4 o; float t;
  t = us.x + vd.x + ab.x; t = (t > 0.f ? t : 0.2f * t) * w; o.x = __expf(t);
  t = us.y + vd.y + ab.y; t = (t > 0.f ? t : 0.2f * t) * w; o.y = __expf(t);
  t = us.z + vd.z + ab.z; t = (t > 0.f ? t : 0.2f * t) * w; o.z = __expf(t);
  t = us.w + vd.w + ab.w; t = (t > 0.f ? t : 0.2f * t) * w; o.w = __expf(t);
  est[e] = o;
}

// ---------------- CSR offsets: block-local scan + block sums ---------------
__global__ __launch_bounds__(256) void scan1(const int* __restrict__ deg,
    int* __restrict__ offs, int* __restrict__ bsums, int N)
{
  int i = blockIdx.x * 256 + threadIdx.x;
  int lane = threadIdx.x & 63;
  int w = threadIdx.x >> 6;
  int v = (i < N) ? deg[i] : 0;
  int s = v;
  #pragma unroll
  for (int d = 1; d < 64; d <<= 1) {
    int t = __shfl_up(s, d, 64);
    if (lane >= d) s += t;
  }
  __shared__ int wsum[4];
  if (lane == 63) wsum[w] = s;
  __syncthreads();
  int add = 0;
  if (w > 0) add += wsum[0];
  if (w > 1) add += wsum[1];
  if (w > 2) add += wsum[2];
  if (i < N) offs[i] = s - v + add;                 // block-exclusive
  if (threadIdx.x == 255) bsums[blockIdx.x] = wsum[0] + wsum[1] + wsum[2] + wsum[3];
}

__global__ __launch_bounds__(512) void scan2(int* bsums, int NB)
{
  __shared__ int lds[512];
  int t = threadIdx.x;
  int v = (t < NB) ? bsums[t] : 0;
  lds[t] = v;
  __syncthreads();
  for (int s = 1; s < 512; s <<= 1) {
    int a = (t >= s) ? lds[t - s] : 0;
    __syncthreads();
    lds[t] += a;
    __syncthreads();
  }
  if (t < NB) bsums[t] = lds[t] - v;                // exclusive
}

// -------- CSR fill: scatter src + es value, no atomics ---------------------
__global__ __launch_bounds__(256) void k_fill(const int* __restrict__ ei,
    const int* __restrict__ offs, const int* __restrict__ bsums,
    const int* __restrict__ rank, const float4* __restrict__ est,
    int* __restrict__ csr_src, float4* __restrict__ csr_es, int E)
{
  int e = blockIdx.x * 256 + threadIdx.x;
  if (e >= E) return;
  int d = ei[E + e];
  int pos = offs[d] + bsums[d >> 8] + rank[e];
  csr_src[pos] = ei[e];
  csr_es[pos] = est[e];
}

// -------- aggregation: wave/node, maskless pipelined 4-edge groups ---------
__global__ __launch_bounds__(256) void k_agg(const unsigned short* __restrict__ h16,
    const int* __restrict__ csr_src, const float4* __restrict__ csr_es,
    const int* __restrict__ offs, const int* __restrict__ bsums,
    unsigned short* __restrict__ agg, int N, int E)
{
  const int c = threadIdx.x & 63;
  const int wid = blockIdx.x * 4 + (threadIdx.x >> 6);
  const int wstride = gridDim.x * 4;

  for (int n0 = wid; n0 < N; n0 += wstride) {
    const int n = __builtin_amdgcn_readfirstlane(n0);
    const int p0 = offs[n] + bsums[n >> 8];
    const int p1 = (n + 1 < N) ? (offs[n + 1] + bsums[(n + 1) >> 8]) : E;
    const int nf = (p1 - p0) & ~3;                  // full-group edge count

    float acc0 = 0.f, acc1 = 0.f, acc2 = 0.f, acc3 = 0.f;
    float den0 = 0.f, den1 = 0.f, den2 = 0.f, den3 = 0.f;

    int4   sA = make_int4(0, 0, 0, 0);
    float4 eA0, eA1, eA2, eA3;
    float  gA0 = 0.f, gA1 = 0.f, gA2 = 0.f, gA3 = 0.f;
    if (nf) {
      sA = *(const int4*)(csr_src + p0);            // uniform -> s_load
      eA0 = csr_es[p0];     eA1 = csr_es[p0 + 1];   // uniform -> s_load
      eA2 = csr_es[p0 + 2]; eA3 = csr_es[p0 + 3];
      gA0 = bf2f(h16[(size_t)sA.x * 64 + c]);
      gA1 = bf2f(h16[(size_t)sA.y * 64 + c]);
      gA2 = bf2f(h16[(size_t)sA.z * 64 + c]);
      gA3 = bf2f(h16[(size_t)sA.w * 64 + c]);
    }
    for (int p = p0; p < p0 + nf; p += 4) {
      int4 sB; float4 eB0, eB1, eB2, eB3;
      float gB0, gB1, gB2, gB3;
      const bool more = (p + 4 < p0 + nf);
      if (more) {                                   // prefetch next group
        sB = *(const int4*)(csr_src + p + 4);
        eB0 = csr_es[p + 4]; eB1 = csr_es[p + 5];
        eB2 = csr_es[p + 6]; eB3 = csr_es[p + 7];
        gB0 = bf2f(h16[(size_t)sB.x * 64 + c]);
        gB1 = bf2f(h16[(size_t)sB.y * 64 + c]);
        gB2 = bf2f(h16[(size_t)sB.z * 64 + c]);
        gB3 = bf2f(h16[(size_t)sB.w * 64 + c]);
      }
      den0 += (eA0.x + eA1.x) + (eA2.x + eA3.x);
      den1 += (eA0.y + eA1.y) + (eA2.y + eA3.y);
      den2 += (eA0.z + eA1.z) + (eA2.z + eA3.z);
      den3 += (eA0.w + eA1.w) + (eA2.w + eA3.w);
      acc0 = fmaf(eA0.x, gA0, fmaf(eA1.x, gA1, fmaf(eA2.x, gA2, fmaf(eA3.x, gA3, acc0))));
      acc1 = fmaf(eA0.y, gA0, fmaf(eA1.y, gA1, fmaf(eA2.y, gA2, fmaf(eA3.y, gA3, acc1))));
      acc2 = fmaf(eA0.z, gA0, fmaf(eA1.z, gA1, fmaf(eA2.z, gA2, fmaf(eA3.z, gA3, acc2))));
      acc3 = fmaf(eA0.w, gA0, fmaf(eA1.w, gA1, fmaf(eA2.w, gA2, fmaf(eA3.w, gA3, acc3))));
      if (more) {
        eA0 = eB0; eA1 = eB1; eA2 = eB2; eA3 = eB3;
        gA0 = gB0; gA1 = gB1; gA2 = gB2; gA3 = gB3;
      }
    }
    for (int p = p0 + nf; p < p1; ++p) {            // tail (<=3, wave-uniform)
      int s = csr_src[p];
      float4 ev = csr_es[p];
      float g = bf2f(h16[(size_t)s * 64 + c]);
      den0 += ev.x; den1 += ev.y; den2 += ev.z; den3 += ev.w;
      acc0 = fmaf(ev.x, g, acc0);
      acc1 = fmaf(ev.y, g, acc1);
      acc2 = fmaf(ev.z, g, acc2);
      acc3 = fmaf(ev.w, g, acc3);
    }
    ushort4 o;
    o.x = f2bf(acc0 / (den0 + 1e-8f));
    o.y = f2bf(acc1 / (den1 + 1e-8f));
    o.z = f2bf(acc2 / (den2 + 1e-8f));
    o.w = f2bf(acc3 / (den3 + 1e-8f));
    *(ushort4*)(agg + (size_t)n * 256 + c * 4) = o;
  }
}

// ------- pack Pw (256x64 fp32) into bf16 MFMA B-fragment order ------------
__global__ __launch_bounds__(256) void k_pw(const float* __restrict__ Pw,
    unsigned short* __restrict__ Bf)
{
  int i = blockIdx.x * 256 + threadIdx.x;   // 0..16383
  int j    = i & 7;
  int lane = (i >> 3) & 63;
  int cb   = (i >> 9) & 3;
  int ks   = i >> 11;
  int k    = ks * 32 + (lane >> 4) * 8 + j;
  int colg = cb * 16 + (lane & 15);
  Bf[i] = f2bf(Pw[(size_t)k * 64 + colg]);
}

// ------- proj GEMM via MFMA + fused residual/LN/ReLU epilogue -------------
__global__ __launch_bounds__(256) void k_projm(const unsigned short* __restrict__ agg,
    const unsigned short* __restrict__ Bf, const float* __restrict__ x,
    const float* __restrict__ Pb,
    const float* __restrict__ lg, const float* __restrict__ lb,
    float* __restrict__ out, int N)
{
  const int lane = threadIdx.x & 63;
  const int wv = threadIdx.x >> 6;
  const int nt = blockIdx.x * 4 + wv;           // 16-node tile index
  if (nt * 16 >= N) return;
  const int col  = lane & 15;
  const int quad = lane >> 4;
  const int base = nt * 16;

  int na = base + col; if (na >= N) na = N - 1;
  const unsigned short* aptr = agg + (size_t)na * 256 + quad * 8;

  f32x4 acc0 = {0.f, 0.f, 0.f, 0.f};
  f32x4 acc1 = {0.f, 0.f, 0.f, 0.f};
  f32x4 acc2 = {0.f, 0.f, 0.f, 0.f};
  f32x4 acc3 = {0.f, 0.f, 0.f, 0.f};

  #pragma unroll
  for (int ks = 0; ks < 8; ++ks) {
    bf16x8 av = *(const bf16x8*)(aptr + ks * 32);
    bf16x8 b0 = *(const bf16x8*)(Bf + ((size_t)(ks * 4 + 0) * 64 + lane) * 8);
    bf16x8 b1 = *(const bf16x8*)(Bf + ((size_t)(ks * 4 + 1) * 64 + lane) * 8);
    bf16x8 b2 = *(const bf16x8*)(Bf + ((size_t)(ks * 4 + 2) * 64 + lane) * 8);
    bf16x8 b3 = *(const bf16x8*)(Bf + ((size_t)(ks * 4 + 3) * 64 + lane) * 8);
    acc0 = __builtin_amdgcn_mfma_f32_16x16x32_bf16(av, b0, acc0, 0, 0, 0);
    acc1 = __builtin_amdgcn_mfma_f32_16x16x32_bf16(av, b1, acc1, 0, 0, 0);
    acc2 = __builtin_amdgcn_mfma_f32_16x16x32_bf16(av, b2, acc2, 0, 0, 0);
    acc3 = __builtin_amdgcn_mfma_f32_16x16x32_bf16(av, b3, acc3, 0, 0, 0);
  }

  const float pb0 = Pb[col], pb1 = Pb[16 + col], pb2 = Pb[32 + col], pb3 = Pb[48 + col];
  float v[4][4];                                 // [cb][reg]
  #pragma unroll
  for (int r = 0; r < 4; ++r) {
    int node = base + quad * 4 + r; if (node >= N) node = N - 1;
    const float* xr = x + (size_t)node * 64;
    v[0][r] = acc0[r] + pb0 + xr[col];
    v[1][r] = acc1[r] + pb1 + xr[16 + col];
    v[2][r] = acc2[r] + pb2 + xr[32 + col];
    v[3][r] = acc3[r] + pb3 + xr[48 + col];
  }

  float mu[4], inv[4];
  #pragma unroll
  for (int r = 0; r < 4; ++r) {
    float s = (v[0][r] + v[1][r]) + (v[2][r] + v[3][r]);
    s += __shfl_xor(s, 1, 64); s += __shfl_xor(s, 2, 64);
    s += __shfl_xor(s, 4, 64); s += __shfl_xor(s, 8, 64);
    mu[r] = s * 0.015625f;
  }
  #pragma unroll
  for (int r = 0; r < 4; ++r) {
    float d0 = v[0][r] - mu[r], d1 = v[1][r] - mu[r];
    float d2 = v[2][r] - mu[r], d3 = v[3][r] - mu[r];
    float s = fmaf(d0, d0, d1 * d1) + fmaf(d2, d2, d3 * d3);
    s += __shfl_xor(s, 1, 64); s += __shfl_xor(s, 2, 64);
    s += __shfl_xor(s, 4, 64); s += __shfl_xor(s, 8, 64);
    inv[r] = rsqrtf(s * 0.015625f + 1e-5f);
  }

  const float lg0 = lg[col], lg1 = lg[16 + col], lg2 = lg[32 + col], lg3 = lg[48 + col];
  const float lb0 = lb[col], lb1 = lb[16 + col], lb2 = lb[32 + col], lb3 = lb[48 + col];
  #pragma unroll
  for (int r = 0; r < 4; ++r) {
    int node = base + quad * 4 + r;
    if (node < N) {
      float* orow = out + (size_t)node * 64;
      orow[col]      = fmaxf(fmaf(lg0 * (v[0][r] - mu[r]), inv[r], lb0), 0.f);
      orow[16 + col] = fmaxf(fmaf(lg1 * (v[1][r] - mu[r]), inv[r], lb1), 0.f);
      orow[32 + col] = fmaxf(fmaf(lg2 * (v[2][r] - mu[r]), inv[r], lb2), 0.f);
      orow[48 + col] = fmaxf(fmaf(lg3 * (v[3][r] - mu[r]), inv[r], lb3), 0.f);
    }
  }
}

// ---------------------------------------------------------------------------
extern "C" void kernel_launch(void* const* d_in, const int* in_sizes, int n_in,
                              void* d_out, int out_size, void* d_ws, size_t ws_size,
                              hipStream_t stream)
{
  const float* x  = (const float*)d_in[0];
  const int*   ei = (const int*)d_in[1];
  const float* et = (const float*)d_in[2];
  const int*   ct = (const int*)d_in[3];
  const float* Ww = (const float*)d_in[4];
  const float* Wb = (const float*)d_in[5];
  const float* aw = (const float*)d_in[6];
  const float* ab = (const float*)d_in[7];
  const float* dr = (const float*)d_in[8];
  const float* Pw = (const float*)d_in[9];
  const float* Pb = (const float*)d_in[10];
  const float* lg = (const float*)d_in[11];
  const float* lb = (const float*)d_in[12];
  float* out = (float*)d_out;

  const int N = in_sizes[0] / 64;
  const int E = in_sizes[2];

  char* ws = (char*)d_ws;
  size_t off = 0;
  auto take = [&](size_t bytes) -> char* {
    char* p = ws + off;
    off = (off + bytes + 255) & ~(size_t)255;
    return p;
  };
  unsigned short* h16 = (unsigned short*)take((size_t)N * 64 * 2);
  int*    deg    = (int*)take((size_t)N * 4);
  int*    offs   = (int*)take((size_t)N * 4);
  int*    bsums  = (int*)take(512 * 4);
  int*    rank   = (int*)take((size_t)E * 4);
  float4* est    = (float4*)take((size_t)E * 16);
  int*    csr_src= (int*)take((size_t)E * 4);
  float4* csr_es = (float4*)take((size_t)E * 16);
  unsigned short* agg = (unsigned short*)take((size_t)N * 256 * 2);
  float4* u      = (float4*)take((size_t)N * 16);
  float4* v      = (float4*)take((size_t)N * 16);
  unsigned short* Bf = (unsigned short*)take(16384 * 2);

  hipMemsetAsync(deg, 0, (size_t)N * 4, stream);

  k_pw<<<64, 256, 0, stream>>>(Pw, Bf);
  k_hn<<<(N + 63) / 64, 64, 0, stream>>>(x, Ww, Wb, aw, h16, u, v, N);
  k_score<<<(E + 255) / 256, 256, 0, stream>>>(u, v, ei, et, ct, dr, ab, est, deg, rank, E);
  const int NB = (N + 255) / 256;
  scan1<<<NB, 256, 0, stream>>>(deg, offs, bsums, N);
  scan2<<<1, 512, 0, stream>>>(bsums, NB);
  k_fill<<<(E + 255) / 256, 256, 0, stream>>>(ei, offs, bsums, rank, est, csr_src, csr_es, E);
  k_agg<<<2048, 256, 0, stream>>>(h16, csr_src, csr_es, offs, bsums, agg, N, E);
  const int NT = (N + 15) / 16;
  k_projm<<<(NT + 3) / 4, 256, 0, stream>>>(agg, Bf, x, Pb, lg, lb, out, N);
}